// Round 1
// baseline (325.431 us; speedup 1.0000x reference)
//
#include <hip/hip_runtime.h>
#include <math.h>

typedef __attribute__((ext_vector_type(8))) short short8;
typedef __attribute__((ext_vector_type(4))) float f32x4;
typedef __attribute__((ext_vector_type(2))) float f32x2;

#define LRELU(x) ((x) > 0.0f ? (x) : 0.01f * (x))

__device__ __forceinline__ float bf2f(unsigned short h) {
    return __uint_as_float(((unsigned int)h) << 16);
}
__device__ __forceinline__ unsigned short f2bf(float f) {
    unsigned int u = __float_as_uint(f);
    return (unsigned short)((u + 0x7FFFu + ((u >> 16) & 1u)) >> 16);
}
// round-half-up bf16 pair pack: ~5 VALU vs ~10 for RNE; <=0.5 ULP error
__device__ __forceinline__ unsigned int pack_bf16_pair(float lo, float hi) {
    unsigned int ul = __float_as_uint(lo) + 0x8000u;
    unsigned int uh = __float_as_uint(hi) + 0x8000u;
    return (ul >> 16) | (uh & 0xFFFF0000u);
}
__device__ __forceinline__ float2 stats_from(const float* sums, int b, float count) {
    float s = sums[2 * b], q = sums[2 * b + 1];
    float mean = s / count;
    float var = (q - s * s / count) / (count - 1.0f);  // ddof=1
    var = fmaxf(var, 0.0f);
    return make_float2(mean, 1.0f / (sqrtf(var) + 1e-5f));
}
// init pattern 0xFFFFFFFF (-NaN): positives via signed max, negatives via unsigned min
__device__ __forceinline__ void atomicMaxF(float* a, float v) {
    if (v >= 0.0f) atomicMax((int*)a, __float_as_int(v));
    else           atomicMin((unsigned int*)a, __float_as_uint(v));
}
// y = lrelu(x * a + c) on a packed bf16 pair, via packed-f32 (VOP3P) ops
__device__ __forceinline__ unsigned int norm_pair(unsigned int u, float a, float c) {
    f32x2 v;
    v.x = __uint_as_float(u << 16);
    v.y = __uint_as_float(u & 0xFFFF0000u);
    v = v * a + c;
    f32x2 m = v * 0.01f;
    v = __builtin_elementwise_max(v, m);
    return pack_bf16_pair(v.x, v.y);
}
__device__ __forceinline__ uint4 norm8(uint4 v, float a, float c) {
    v.x = norm_pair(v.x, a, c); v.y = norm_pair(v.y, a, c);
    v.z = norm_pair(v.z, a, c); v.w = norm_pair(v.w, a, c);
    return v;
}
// 4 fp8 e4m3 (one uint) -> lrelu(x*a+c) -> 4 bf16 (uint2). HW cvt replaces the
// bf16 unpack shifts, so VALU cost matches the bf16 norm path.
__device__ __forceinline__ uint2 fp8x4_nl(unsigned int u, float a, float c) {
    f32x2 lo = __builtin_amdgcn_cvt_pk_f32_fp8(u, false);
    f32x2 hi = __builtin_amdgcn_cvt_pk_f32_fp8(u, true);
    lo = lo * a + c; hi = hi * a + c;
    f32x2 ml = lo * 0.01f, mh = hi * 0.01f;
    lo = __builtin_elementwise_max(lo, ml);
    hi = __builtin_elementwise_max(hi, mh);
    uint2 r;
    r.x = pack_bf16_pair(lo.x, lo.y);
    r.y = pack_bf16_pair(hi.x, hi.y);
    return r;
}

// MFMA fragment block: LDS -> frags -> 2 k-stages of 16x16x32 bf16 MFMAs
template <int MT, int WM>
__device__ __forceinline__ void mfma_step(const unsigned short* wt, const unsigned short* gt,
                                          f32x4 (&acc)[MT][4],
                                          int wo, int wn, int quad, int l15, int blkid)
{
#pragma unroll
    for (int st = 0; st < 2; ++st) {
        short8 af[MT], bfv[4];
        const int qb = st * 4 + quad;
#pragma unroll
        for (int i = 0; i < MT; i++) {
            const int orow = wo * WM + i * 16 + l15;
            af[i] = *(const short8*)&wt[orow * 64 + ((qb ^ blkid) << 3)];
        }
#pragma unroll
        for (int t = 0; t < 4; t++) {
            const int nrow = wn * 64 + t * 16 + l15;
            bfv[t] = *(const short8*)&gt[nrow * 64 + ((qb ^ blkid) << 3)];
        }
#pragma unroll
        for (int i = 0; i < MT; i++)
#pragma unroll
            for (int t = 0; t < 4; t++)
                acc[i][t] = __builtin_amdgcn_mfma_f32_16x16x32_bf16(
                    af[i], bfv[t], acc[i][t], 0, 0, 0);
    }
}

// w [O][Cin][3] f32  ->  wq [O][3*Cin] bf16 with k' = j*Cin + c
__global__ void prep_weights(const float* __restrict__ w, unsigned short* __restrict__ wq,
                             int O, int Cin)
{
    const int K = 3 * Cin, total = O * K;
    for (int i = blockIdx.x * blockDim.x + threadIdx.x; i < total;
         i += gridDim.x * blockDim.x) {
        int o = i / K, kp = i - o * K;
        int j = kp / Cin, c = kp - j * Cin;
        wq[i] = f2bf(w[(o * Cin + c) * 3 + j]);
    }
}

// data [128][64][1024] f32 -> xT [nB][1024][64] bf16 (tower select on b>=128)
__global__ __launch_bounds__(256) void transpose_in(const float* __restrict__ inA,
                                                    const float* __restrict__ inB,
                                                    unsigned short* __restrict__ xT)
{
    const int b = blockIdx.y, n0 = blockIdx.x * 64;
    const float* in = (b >= 128 ? inB : inA) + ((size_t)(b & 127) * 64) * 1024;
    const int tid = threadIdx.x;
    __shared__ float tile[64][65];
    const int nn = tid & 63, cw = tid >> 6;
#pragma unroll
    for (int i = 0; i < 16; i++) {
        int c = i * 4 + cw;
        tile[c][nn] = in[(size_t)c * 1024 + n0 + nn];
    }
    __syncthreads();
    const int n = tid >> 2, cp = (tid & 3) * 16;
    unsigned int pk[8];
#pragma unroll
    for (int i = 0; i < 8; i++) {
        unsigned short lo = f2bf(tile[cp + 2 * i][n]);
        unsigned short hi = f2bf(tile[cp + 2 * i + 1][n]);
        pk[i] = (unsigned int)lo | ((unsigned int)hi << 16);
    }
    unsigned short* dst = xT + ((size_t)b * 1024 + n0 + n) * 64 + cp;
    uint4 v0 = {pk[0], pk[1], pk[2], pk[3]};
    uint4 v1 = {pk[4], pk[5], pk[6], pk[7]};
    *(uint4*)dst = v0;
    *(uint4*)(dst + 8) = v1;
}

// MFMA gather-conv, register-staged 2-deep pipelined K-loop (named scalars only:
// local arrays fail SROA -> scratch, the R5-R7 600MB bug).
// FP8IN:  gathered tensor is fp8 e4m3; decode fused into the norm step.
// FP8OUT: epilogue stores fp8 e4m3 via v_cvt_pk_fp8_f32 (halves streaming writes).
// R11 diagnosis: conv2 is random-access-HBM-bound (~2.2 TB/s on 128B granules,
// FETCH = 1x compulsory pass of a1) -> bytes are the lever, hence fp8 a1.
// __launch_bounds__(256, 2) EXACTLY: (256,4) spills staging (R9). Do not raise.
template <int BM, bool POOL, bool NORM, bool FP8IN, bool FP8OUT>
__global__ __launch_bounds__(256, 2) void conv_mfma(
    const void* __restrict__ xTv,            // [nB][1024][Cin] bf16 or fp8 (raw)
    const int* __restrict__ idxA,            // [128][3069]
    const int* __restrict__ idxB,
    const unsigned short* __restrict__ wq,   // [O][K] bf16 (k'=j*Cin+c)
    const float* __restrict__ bias,          // [O] f32
    void* __restrict__ out,                  // [nB][1024][O] bf16/fp8 (unused if POOL)
    float* __restrict__ sums,                // [nB][2] accum (this layer's raw stats)
    float* __restrict__ pmax,                // [nB][64] (POOL only)
    const float* __restrict__ normSums,      // [nB][2] prev-layer stats (NORM only)
    float normCount, int Cin, int cinShift, int O, int K)
{
    constexpr int WM = BM / 2, MT = WM / 16;
    constexpr int NW = (BM == 128) ? 4 : 2;      // 16B packets of wt per thread
    const int b   = blockIdx.x;
    const int o0  = blockIdx.y * BM;
    const int nt0 = blockIdx.z << 7;
    const int tid = threadIdx.x;
    const int lane = tid & 63, wave = tid >> 6;
    const int wo = wave & 1, wn = wave >> 1;
    const int quad = lane >> 4, l15 = lane & 15;
    const int blkid = lane & 7;

    __shared__ __align__(16) unsigned short wt[BM * 64];
    __shared__ __align__(16) unsigned short gt[128 * 64];

    f32x4 acc[MT][4];
#pragma unroll
    for (int i = 0; i < MT; i++)
#pragma unroll
        for (int t = 0; t < 4; t++) acc[i][t] = (f32x4){0.f, 0.f, 0.f, 0.f};

    const unsigned short* xTb16 = (const unsigned short*)xTv + (((size_t)b) << 10) * (size_t)Cin;
    const unsigned char*  xTb8  = (const unsigned char*)xTv  + (((size_t)b) << 10) * (size_t)Cin;
    const int* idxb = (b >= 128 ? idxB : idxA) + (size_t)(b & 127) * 3069;

    float na = 1.0f, nc = 0.0f;
    if (NORM) {
        float2 st = stats_from(normSums, b, normCount);
        na = st.y; nc = -st.x * st.y;
    }

    // --- staging mapping ---
    const int gr = tid >> 1, gh = tid & 1;       // gt row (n), 32-channel half
    int s0, s1, s2;
    {
        int n = nt0 + gr;
        int t0 = (n == 0) ? 0 : (n - 1);         // n==0 row is garbage, zeroed later
        s0 = idxb[3 * t0]; s1 = idxb[3 * t0 + 1]; s2 = idxb[3 * t0 + 2];
    }
    const int wr   = (BM == 128) ? (tid >> 1) : (tid >> 2);  // wt row (o)
    const int wseg = (BM == 128) ? (tid & 1) : (tid & 3);    // segment of NW packets
    const unsigned short* wrow = wq + (size_t)(o0 + wr) * K + wseg * (NW * 8);
    const int gswz = gr & 7, wswz = wr & 7;

    // two independent staging sets (pipeline depth 2), all named scalars
    uint4 g0A, g1A, g2A, g3A, w0A, w1A, w2A, w3A;
    uint4 g0B, g1B, g2B, g3B, w0B, w1B, w2B, w3B;

#define LOADC(S, KC) {                                                           \
        const int k64_ = (KC) << 6;                                              \
        const int j_   = k64_ >> cinShift;                                       \
        const int c0_  = k64_ & (Cin - 1);                                       \
        const int src_ = (j_ == 0) ? s0 : ((j_ == 1) ? s1 : s2);                 \
        if (FP8IN) {                                                             \
            const uint4* gp_ = (const uint4*)(xTb8 + (size_t)src_ * Cin + c0_ + gh * 32); \
            g0##S = gp_[0]; g1##S = gp_[1];                                      \
        } else {                                                                 \
            const uint4* gp_ = (const uint4*)(xTb16 + (size_t)src_ * Cin + c0_ + gh * 32); \
            g0##S = gp_[0]; g1##S = gp_[1]; g2##S = gp_[2]; g3##S = gp_[3];      \
        }                                                                        \
        const uint4* wp_ = (const uint4*)(wrow + k64_);                          \
        w0##S = wp_[0]; w1##S = wp_[1];                                          \
        if (NW == 4) { w2##S = wp_[2]; w3##S = wp_[3]; }                         \
    }

#define STAGE(S) {                                                               \
        uint4 h0, h1, h2, h3;                                                    \
        if (FP8IN) {                                                             \
            uint2 p0 = fp8x4_nl(g0##S.x, na, nc), p1 = fp8x4_nl(g0##S.y, na, nc);\
            uint2 p2 = fp8x4_nl(g0##S.z, na, nc), p3 = fp8x4_nl(g0##S.w, na, nc);\
            h0.x = p0.x; h0.y = p0.y; h0.z = p1.x; h0.w = p1.y;                  \
            h1.x = p2.x; h1.y = p2.y; h1.z = p3.x; h1.w = p3.y;                  \
            p0 = fp8x4_nl(g1##S.x, na, nc); p1 = fp8x4_nl(g1##S.y, na, nc);      \
            p2 = fp8x4_nl(g1##S.z, na, nc); p3 = fp8x4_nl(g1##S.w, na, nc);      \
            h2.x = p0.x; h2.y = p0.y; h2.z = p1.x; h2.w = p1.y;                  \
            h3.x = p2.x; h3.y = p2.y; h3.z = p3.x; h3.w = p3.y;                  \
        } else {                                                                 \
            h0 = g0##S; h1 = g1##S; h2 = g2##S; h3 = g3##S;                      \
            if (NORM) {                                                          \
                h0 = norm8(h0, na, nc); h1 = norm8(h1, na, nc);                  \
                h2 = norm8(h2, na, nc); h3 = norm8(h3, na, nc);                  \
            }                                                                    \
        }                                                                        \
        *(uint4*)&gt[gr * 64 + (((gh << 2) | 0) ^ gswz) * 8] = h0;               \
        *(uint4*)&gt[gr * 64 + (((gh << 2) | 1) ^ gswz) * 8] = h1;               \
        *(uint4*)&gt[gr * 64 + (((gh << 2) | 2) ^ gswz) * 8] = h2;               \
        *(uint4*)&gt[gr * 64 + (((gh << 2) | 3) ^ gswz) * 8] = h3;               \
        *(uint4*)&wt[wr * 64 + ((wseg * NW + 0) ^ wswz) * 8] = w0##S;            \
        *(uint4*)&wt[wr * 64 + ((wseg * NW + 1) ^ wswz) * 8] = w1##S;            \
        if (NW == 4) {                                                           \
            *(uint4*)&wt[wr * 64 + ((wseg * NW + 2) ^ wswz) * 8] = w2##S;        \
            *(uint4*)&wt[wr * 64 + ((wseg * NW + 3) ^ wswz) * 8] = w3##S;        \
        }                                                                        \
    }

    const int nChunks = K >> 6;      // conv1:3, conv2:12, conv3:6
    LOADC(A, 0);
    if (nChunks > 1) LOADC(B, 1);
    int kc = 0;
    for (; kc + 2 <= nChunks; kc += 2) {
        if (kc) __syncthreads();              // prior chunk's LDS readers done
        STAGE(A);                             // waits set-A loads only
        if (kc + 2 < nChunks) LOADC(A, kc + 2);
        __syncthreads();
        mfma_step<MT, WM>(wt, gt, acc, wo, wn, quad, l15, blkid);
        __syncthreads();
        STAGE(B);
        if (kc + 3 < nChunks) LOADC(B, kc + 3);
        __syncthreads();
        mfma_step<MT, WM>(wt, gt, acc, wo, wn, quad, l15, blkid);
    }
    if (kc < nChunks) {                       // odd tail (conv1: chunk 2 in set A)
        __syncthreads();
        STAGE(A);
        __syncthreads();
        mfma_step<MT, WM>(wt, gt, acc, wo, wn, quad, l15, blkid);
    }
#undef LOADC
#undef STAGE

    // epilogue: bias, zero col 0, store (unless POOL), fused stats, fused max-pool
    float lsum = 0.f, lsq = 0.f;
#pragma unroll
    for (int i = 0; i < MT; i++) {
        const int ob = o0 + wo * WM + i * 16 + quad * 4;
        const float4 bv = *(const float4*)(bias + ob);
        float mx0 = -1e30f, mx1 = -1e30f, mx2 = -1e30f, mx3 = -1e30f;
#pragma unroll
        for (int t = 0; t < 4; t++) {
            const int n = nt0 + wn * 64 + t * 16 + l15;
            float v0 = acc[i][t][0] + bv.x;
            float v1 = acc[i][t][1] + bv.y;
            float v2 = acc[i][t][2] + bv.z;
            float v3 = acc[i][t][3] + bv.w;
            if (n == 0) { v0 = v1 = v2 = v3 = 0.f; }
            lsum += v0 + v1 + v2 + v3;
            lsq  += v0 * v0 + v1 * v1 + v2 * v2 + v3 * v3;
            if (POOL) {
                mx0 = fmaxf(mx0, v0); mx1 = fmaxf(mx1, v1);
                mx2 = fmaxf(mx2, v2); mx3 = fmaxf(mx3, v3);
            } else if (FP8OUT) {
                int r = __builtin_amdgcn_cvt_pk_fp8_f32(v0, v1, 0, false);
                r = __builtin_amdgcn_cvt_pk_fp8_f32(v2, v3, r, true);
                *(unsigned int*)&((unsigned char*)out)[((size_t)b * 1024 + n) * O + ob] =
                    (unsigned int)r;
            } else {
                uint2 pk;
                pk.x = pack_bf16_pair(v0, v1);
                pk.y = pack_bf16_pair(v2, v3);
                *(uint2*)&((unsigned short*)out)[((size_t)b * 1024 + n) * O + ob] = pk;
            }
        }
        if (POOL) {
#pragma unroll
            for (int off = 1; off < 16; off <<= 1) {
                mx0 = fmaxf(mx0, __shfl_xor(mx0, off));
                mx1 = fmaxf(mx1, __shfl_xor(mx1, off));
                mx2 = fmaxf(mx2, __shfl_xor(mx2, off));
                mx3 = fmaxf(mx3, __shfl_xor(mx3, off));
            }
            if (l15 == 0) {
                atomicMaxF(&pmax[(size_t)b * 64 + ob + 0], mx0);
                atomicMaxF(&pmax[(size_t)b * 64 + ob + 1], mx1);
                atomicMaxF(&pmax[(size_t)b * 64 + ob + 2], mx2);
                atomicMaxF(&pmax[(size_t)b * 64 + ob + 3], mx3);
            }
        }
    }
#pragma unroll
    for (int off = 32; off > 0; off >>= 1) {
        lsum += __shfl_down(lsum, off);
        lsq  += __shfl_down(lsq, off);
    }
    float* red = (float*)wt;  // wt dead after K-loop
    if (lane == 0) { red[wave] = lsum; red[4 + wave] = lsq; }
    __syncthreads();
    if (tid == 0) {
        atomicAdd(&sums[2 * b + 0], red[0] + red[1] + red[2] + red[3]);
        atomicAdd(&sums[2 * b + 1], red[4] + red[5] + red[6] + red[7]);
    }
}

// pooled max -> normalize -> fc1+lrelu -> fc2
__global__ __launch_bounds__(64) void fc_head(
    const float* __restrict__ pmax, const float* __restrict__ sums3, float count,
    const float* __restrict__ w_fc1, const float* __restrict__ b_fc1,
    const float* __restrict__ w_fc2, const float* __restrict__ b_fc2,
    float* __restrict__ y)
{
    const int b = blockIdx.x, t = threadIdx.x;
    __shared__ float pooled[64];
    __shared__ float hid[32];
    float2 s = stats_from(sums3, b, count);
    pooled[t] = (pmax[(size_t)b * 64 + t] - s.x) * s.y;
    __syncthreads();
    if (t < 32) {
        float h = b_fc1[t];
#pragma unroll
        for (int c = 0; c < 64; c++) h += pooled[c] * w_fc1[t * 64 + c];
        hid[t] = LRELU(h);
    }
    __syncthreads();
    if (t == 0) {
        float v = b_fc2[0];
#pragma unroll
        for (int c = 0; c < 32; c++) v += hid[c] * w_fc2[c];
        y[b] = v;
    }
}

__global__ void sigmoid_diff(const float* __restrict__ y1,
                             const float* __restrict__ y2,
                             float* __restrict__ out)
{
    int b = threadIdx.x;
    if (b < 128) out[b] = 1.0f / (1.0f + expf(-(y1[b] - y2[b])));
}

extern "C" void kernel_launch(void* const* d_in, const int* in_sizes, int n_in,
                              void* d_out, int out_size, void* d_ws, size_t ws_size,
                              hipStream_t stream)
{
    const float* data1 = (const float*)d_in[0];
    const int*   idx1  = (const int*)d_in[1];
    const float* data2 = (const float*)d_in[2];
    const int*   idx2  = (const int*)d_in[3];
    const float* w1 = (const float*)d_in[4];
    const float* b1 = (const float*)d_in[5];
    const float* w2 = (const float*)d_in[6];
    const float* b2 = (const float*)d_in[7];
    const float* w3 = (const float*)d_in[8];
    const float* b3 = (const float*)d_in[9];
    const float* wfc1 = (const float*)d_in[10];
    const float* bfc1 = (const float*)d_in[11];
    const float* wfc2 = (const float*)d_in[12];
    const float* bfc2 = (const float*)d_in[13];

    // a1 is fp8 (1B/elem); xT and a2 stay bf16
    const size_t needM = (size_t)256 * 1024 * (64 * 2 + 256 * 1 + 128 * 2) + 768 * 1024;
    const bool merged = ws_size >= needM;
    const int nB = merged ? 256 : 128;
    const size_t szXT = (size_t)nB * 1024 * 64 * 2;
    const size_t szA1 = (size_t)nB * 1024 * 256;       // fp8
    const size_t szA2 = (size_t)nB * 1024 * 128 * 2;

    char* ws = (char*)d_ws;
    unsigned short* xT = (unsigned short*)ws;
    unsigned char*  a1 = (unsigned char*)(ws + szXT);
    unsigned short* a2 = (unsigned short*)(ws + szXT + szA1);
    char* tail = ws + szXT + szA1 + szA2;
    unsigned short* wq1 = (unsigned short*)tail;                 // 96 KB
    unsigned short* wq2 = (unsigned short*)(tail + 128 * 1024);  // 192 KB
    unsigned short* wq3 = (unsigned short*)(tail + 384 * 1024);  // 48 KB
    float* sums = (float*)(tail + 448 * 1024);                   // 3*nB*2 f32
    float* pmax = (float*)(tail + 512 * 1024);                   // nB*64 f32
    float* yv   = (float*)(tail + 640 * 1024);                   // 256 f32

    prep_weights<<<96, 256, 0, stream>>>(w1, wq1, 256, 64);
    prep_weights<<<96, 256, 0, stream>>>(w2, wq2, 128, 256);
    prep_weights<<<96, 256, 0, stream>>>(w3, wq3, 64, 128);

    const int nIter = merged ? 1 : 2;
    for (int t = 0; t < nIter; ++t) {
        const float* dA = (merged || t == 0) ? data1 : data2;
        const float* dB = merged ? data2 : dA;
        const int* iA = (merged || t == 0) ? idx1 : idx2;
        const int* iB = merged ? idx2 : iA;
        float* s1 = sums;
        float* s2 = sums + nB * 2;
        float* s3 = sums + nB * 4;

        hipMemsetAsync(sums, 0, 3 * (size_t)nB * 2 * sizeof(float), stream);
        hipMemsetAsync(pmax, 0xFF, (size_t)nB * 64 * sizeof(float), stream);

        transpose_in<<<dim3(16, nB), 256, 0, stream>>>(dA, dB, xT);

        // conv1: bf16 in, fp8 out (halves the 134MB streaming write)
        conv_mfma<128, false, false, false, true><<<dim3(nB, 2, 8), 256, 0, stream>>>(
            xT, iA, iB, wq1, b1, a1, s1, nullptr, nullptr, 0.0f, 64, 6, 256, 192);

        // conv2: fp8 in (halves the random-gather HBM read), bf16 out
        conv_mfma<128, false, true, true, false><<<dim3(nB, 1, 8), 256, 0, stream>>>(
            a1, iA, iB, wq2, b2, a2, s2, nullptr, s1, 256.0f * 1024.0f, 256, 8, 128, 768);

        conv_mfma<64, true, true, false, false><<<dim3(nB, 1, 8), 256, 0, stream>>>(
            a2, iA, iB, wq3, b3, nullptr, s3, pmax, s2, 128.0f * 1024.0f, 128, 7, 64, 384);

        fc_head<<<nB, 64, 0, stream>>>(pmax, s3, 64.0f * 1024.0f,
                                       wfc1, bfc1, wfc2, bfc2,
                                       yv + (merged ? 0 : t * 128));
    }
    sigmoid_diff<<<1, 128, 0, stream>>>(yv, yv + 128, (float*)d_out);
}

// Round 2
// 324.070 us; speedup vs baseline: 1.0042x; 1.0042x over previous
//
#include <hip/hip_runtime.h>
#include <math.h>

typedef __attribute__((ext_vector_type(8))) short short8;
typedef __attribute__((ext_vector_type(4))) float f32x4;
typedef __attribute__((ext_vector_type(2))) float f32x2;

#define LRELU(x) ((x) > 0.0f ? (x) : 0.01f * (x))

__device__ __forceinline__ float bf2f(unsigned short h) {
    return __uint_as_float(((unsigned int)h) << 16);
}
__device__ __forceinline__ unsigned short f2bf(float f) {
    unsigned int u = __float_as_uint(f);
    return (unsigned short)((u + 0x7FFFu + ((u >> 16) & 1u)) >> 16);
}
// round-half-up bf16 pair pack: ~5 VALU vs ~10 for RNE; <=0.5 ULP error
__device__ __forceinline__ unsigned int pack_bf16_pair(float lo, float hi) {
    unsigned int ul = __float_as_uint(lo) + 0x8000u;
    unsigned int uh = __float_as_uint(hi) + 0x8000u;
    return (ul >> 16) | (uh & 0xFFFF0000u);
}
__device__ __forceinline__ float2 stats_from(const float* sums, int b, float count) {
    float s = sums[2 * b], q = sums[2 * b + 1];
    float mean = s / count;
    float var = (q - s * s / count) / (count - 1.0f);  // ddof=1
    var = fmaxf(var, 0.0f);
    return make_float2(mean, 1.0f / (sqrtf(var) + 1e-5f));
}
// init pattern 0xFFFFFFFF (-NaN): positives via signed max, negatives via unsigned min
__device__ __forceinline__ void atomicMaxF(float* a, float v) {
    if (v >= 0.0f) atomicMax((int*)a, __float_as_int(v));
    else           atomicMin((unsigned int*)a, __float_as_uint(v));
}
// y = lrelu(x * a + c) on a packed bf16 pair, via packed-f32 (VOP3P) ops
__device__ __forceinline__ unsigned int norm_pair(unsigned int u, float a, float c) {
    f32x2 v;
    v.x = __uint_as_float(u << 16);
    v.y = __uint_as_float(u & 0xFFFF0000u);
    v = v * a + c;
    f32x2 m = v * 0.01f;
    v = __builtin_elementwise_max(v, m);
    return pack_bf16_pair(v.x, v.y);
}
__device__ __forceinline__ uint4 norm8(uint4 v, float a, float c) {
    v.x = norm_pair(v.x, a, c); v.y = norm_pair(v.y, a, c);
    v.z = norm_pair(v.z, a, c); v.w = norm_pair(v.w, a, c);
    return v;
}
// 4 fp8 e4m3 -> lrelu(x*a+c) -> 4 fp8 e4m3 (in-register, for the norm_act pass)
__device__ __forceinline__ unsigned int fp8x4_nact(unsigned int u, float a, float c) {
    f32x2 lo = __builtin_amdgcn_cvt_pk_f32_fp8(u, false);
    f32x2 hi = __builtin_amdgcn_cvt_pk_f32_fp8(u, true);
    lo = lo * a + c; hi = hi * a + c;
    f32x2 ml = lo * 0.01f, mh = hi * 0.01f;
    lo = __builtin_elementwise_max(lo, ml);
    hi = __builtin_elementwise_max(hi, mh);
    int r = __builtin_amdgcn_cvt_pk_fp8_f32(lo.x, lo.y, 0, false);
    r = __builtin_amdgcn_cvt_pk_fp8_f32(hi.x, hi.y, r, true);
    return (unsigned int)r;
}

// MFMA fragment block (bf16): LDS -> frags -> 2 k-stages of 16x16x32 bf16 MFMAs
template <int MT, int WM>
__device__ __forceinline__ void mfma_step(const unsigned short* wt, const unsigned short* gt,
                                          f32x4 (&acc)[MT][4],
                                          int wo, int wn, int quad, int l15, int blkid)
{
#pragma unroll
    for (int st = 0; st < 2; ++st) {
        short8 af[MT], bfv[4];
        const int qb = st * 4 + quad;
#pragma unroll
        for (int i = 0; i < MT; i++) {
            const int orow = wo * WM + i * 16 + l15;
            af[i] = *(const short8*)&wt[orow * 64 + ((qb ^ blkid) << 3)];
        }
#pragma unroll
        for (int t = 0; t < 4; t++) {
            const int nrow = wn * 64 + t * 16 + l15;
            bfv[t] = *(const short8*)&gt[nrow * 64 + ((qb ^ blkid) << 3)];
        }
#pragma unroll
        for (int i = 0; i < MT; i++)
#pragma unroll
            for (int t = 0; t < 4; t++)
                acc[i][t] = __builtin_amdgcn_mfma_f32_16x16x32_bf16(
                    af[i], bfv[t], acc[i][t], 0, 0, 0);
    }
}

// w [O][Cin][3] f32  ->  wq [O][3*Cin] bf16 with k' = j*Cin + c
__global__ void prep_weights(const float* __restrict__ w, unsigned short* __restrict__ wq,
                             int O, int Cin)
{
    const int K = 3 * Cin, total = O * K;
    for (int i = blockIdx.x * blockDim.x + threadIdx.x; i < total;
         i += gridDim.x * blockDim.x) {
        int o = i / K, kp = i - o * K;
        int j = kp / Cin, c = kp - j * Cin;
        wq[i] = f2bf(w[(o * Cin + c) * 3 + j]);
    }
}

// w [O][Cin][3] f32  ->  wq [O][3*Cin] fp8 e4m3 (for the fp8 MFMA conv2)
__global__ void prep_weights_fp8(const float* __restrict__ w, unsigned char* __restrict__ wq,
                                 int O, int Cin)
{
    const int K = 3 * Cin, total = (O * K) >> 2;
    for (int i = blockIdx.x * blockDim.x + threadIdx.x; i < total;
         i += gridDim.x * blockDim.x) {
        const int e0 = i << 2;
        const int o = e0 / K, kp0 = e0 - o * K;
        float f0, f1, f2, f3;
        {
            int kp = kp0 + 0, j = kp / Cin, c = kp - j * Cin; f0 = w[(o * Cin + c) * 3 + j];
        }
        {
            int kp = kp0 + 1, j = kp / Cin, c = kp - j * Cin; f1 = w[(o * Cin + c) * 3 + j];
        }
        {
            int kp = kp0 + 2, j = kp / Cin, c = kp - j * Cin; f2 = w[(o * Cin + c) * 3 + j];
        }
        {
            int kp = kp0 + 3, j = kp / Cin, c = kp - j * Cin; f3 = w[(o * Cin + c) * 3 + j];
        }
        int r = __builtin_amdgcn_cvt_pk_fp8_f32(f0, f1, 0, false);
        r = __builtin_amdgcn_cvt_pk_fp8_f32(f2, f3, r, true);
        *(unsigned int*)&wq[e0] = (unsigned int)r;
    }
}

// data [128][64][1024] f32 -> xT [nB][1024][64] bf16 (tower select on b>=128)
__global__ __launch_bounds__(256) void transpose_in(const float* __restrict__ inA,
                                                    const float* __restrict__ inB,
                                                    unsigned short* __restrict__ xT)
{
    const int b = blockIdx.y, n0 = blockIdx.x * 64;
    const float* in = (b >= 128 ? inB : inA) + ((size_t)(b & 127) * 64) * 1024;
    const int tid = threadIdx.x;
    __shared__ float tile[64][65];
    const int nn = tid & 63, cw = tid >> 6;
#pragma unroll
    for (int i = 0; i < 16; i++) {
        int c = i * 4 + cw;
        tile[c][nn] = in[(size_t)c * 1024 + n0 + nn];
    }
    __syncthreads();
    const int n = tid >> 2, cp = (tid & 3) * 16;
    unsigned int pk[8];
#pragma unroll
    for (int i = 0; i < 8; i++) {
        unsigned short lo = f2bf(tile[cp + 2 * i][n]);
        unsigned short hi = f2bf(tile[cp + 2 * i + 1][n]);
        pk[i] = (unsigned int)lo | ((unsigned int)hi << 16);
    }
    unsigned short* dst = xT + ((size_t)b * 1024 + n0 + n) * 64 + cp;
    uint4 v0 = {pk[0], pk[1], pk[2], pk[3]};
    uint4 v1 = {pk[4], pk[5], pk[6], pk[7]};
    *(uint4*)dst = v0;
    *(uint4*)(dst + 8) = v1;
}

// R12: apply lrelu(norm(.)) ONCE per a1 element (in place), instead of ~3x inside
// conv2's gather-amplified STAGE. 134 MB streaming traffic ~= 25 us; removes the
// 40%-VALUBusy decode from conv2's K-loop.
__global__ __launch_bounds__(256) void norm_act_fp8(unsigned char* __restrict__ a,
                                                    const float* __restrict__ sums,
                                                    float count)
{
    const int b = blockIdx.y;
    float2 st = stats_from(sums, b, count);
    const float na = st.y, nc = -st.x * st.y;
    uint4* p = (uint4*)(a + ((size_t)b << 18));          // 256 KB per b
    const int base = blockIdx.x * 256 + threadIdx.x;     // grid.x = 16 -> 4096 threads
#pragma unroll
    for (int it = 0; it < 4; ++it) {
        const int idx = base + it * 4096;                // 16384 uint4 per b
        uint4 v = p[idx];
        v.x = fp8x4_nact(v.x, na, nc);
        v.y = fp8x4_nact(v.y, na, nc);
        v.z = fp8x4_nact(v.z, na, nc);
        v.w = fp8x4_nact(v.w, na, nc);
        p[idx] = v;
    }
}

// MFMA gather-conv, register-staged 2-deep pipelined K-loop (named scalars only:
// local arrays fail SROA -> scratch, the R5-R7 600MB bug).
// FP8OUT: epilogue stores fp8 e4m3 via v_cvt_pk_fp8_f32 (halves streaming writes).
// __launch_bounds__(256, 2) EXACTLY: (256,4) spills staging (R9). Do not raise.
template <int BM, bool POOL, bool NORM, bool FP8IN, bool FP8OUT>
__global__ __launch_bounds__(256, 2) void conv_mfma(
    const void* __restrict__ xTv,            // [nB][1024][Cin] bf16 or fp8 (raw)
    const int* __restrict__ idxA,            // [128][3069]
    const int* __restrict__ idxB,
    const unsigned short* __restrict__ wq,   // [O][K] bf16 (k'=j*Cin+c)
    const float* __restrict__ bias,          // [O] f32
    void* __restrict__ out,                  // [nB][1024][O] bf16/fp8 (unused if POOL)
    float* __restrict__ sums,                // [nB][2] accum (this layer's raw stats)
    float* __restrict__ pmax,                // [nB][64] (POOL only)
    const float* __restrict__ normSums,      // [nB][2] prev-layer stats (NORM only)
    float normCount, int Cin, int cinShift, int O, int K)
{
    constexpr int WM = BM / 2, MT = WM / 16;
    constexpr int NW = (BM == 128) ? 4 : 2;      // 16B packets of wt per thread
    const int b   = blockIdx.x;
    const int o0  = blockIdx.y * BM;
    const int nt0 = blockIdx.z << 7;
    const int tid = threadIdx.x;
    const int lane = tid & 63, wave = tid >> 6;
    const int wo = wave & 1, wn = wave >> 1;
    const int quad = lane >> 4, l15 = lane & 15;
    const int blkid = lane & 7;

    __shared__ __align__(16) unsigned short wt[BM * 64];
    __shared__ __align__(16) unsigned short gt[128 * 64];

    f32x4 acc[MT][4];
#pragma unroll
    for (int i = 0; i < MT; i++)
#pragma unroll
        for (int t = 0; t < 4; t++) acc[i][t] = (f32x4){0.f, 0.f, 0.f, 0.f};

    const unsigned short* xTb16 = (const unsigned short*)xTv + (((size_t)b) << 10) * (size_t)Cin;
    const unsigned char*  xTb8  = (const unsigned char*)xTv  + (((size_t)b) << 10) * (size_t)Cin;
    const int* idxb = (b >= 128 ? idxB : idxA) + (size_t)(b & 127) * 3069;

    float na = 1.0f, nc = 0.0f;
    if (NORM) {
        float2 st = stats_from(normSums, b, normCount);
        na = st.y; nc = -st.x * st.y;
    }

    // --- staging mapping ---
    const int gr = tid >> 1, gh = tid & 1;       // gt row (n), 32-channel half
    int s0, s1, s2;
    {
        int n = nt0 + gr;
        int t0 = (n == 0) ? 0 : (n - 1);         // n==0 row is garbage, zeroed later
        s0 = idxb[3 * t0]; s1 = idxb[3 * t0 + 1]; s2 = idxb[3 * t0 + 2];
    }
    const int wr   = (BM == 128) ? (tid >> 1) : (tid >> 2);  // wt row (o)
    const int wseg = (BM == 128) ? (tid & 1) : (tid & 3);    // segment of NW packets
    const unsigned short* wrow = wq + (size_t)(o0 + wr) * K + wseg * (NW * 8);
    const int gswz = gr & 7, wswz = wr & 7;

    // two independent staging sets (pipeline depth 2), all named scalars
    uint4 g0A, g1A, g2A, g3A, w0A, w1A, w2A, w3A;
    uint4 g0B, g1B, g2B, g3B, w0B, w1B, w2B, w3B;

#define LOADC(S, KC) {                                                           \
        const int k64_ = (KC) << 6;                                              \
        const int j_   = k64_ >> cinShift;                                       \
        const int c0_  = k64_ & (Cin - 1);                                       \
        const int src_ = (j_ == 0) ? s0 : ((j_ == 1) ? s1 : s2);                 \
        if (FP8IN) {                                                             \
            const uint4* gp_ = (const uint4*)(xTb8 + (size_t)src_ * Cin + c0_ + gh * 32); \
            g0##S = gp_[0]; g1##S = gp_[1];                                      \
        } else {                                                                 \
            const uint4* gp_ = (const uint4*)(xTb16 + (size_t)src_ * Cin + c0_ + gh * 32); \
            g0##S = gp_[0]; g1##S = gp_[1]; g2##S = gp_[2]; g3##S = gp_[3];      \
        }                                                                        \
        const uint4* wp_ = (const uint4*)(wrow + k64_);                          \
        w0##S = wp_[0]; w1##S = wp_[1];                                          \
        if (NW == 4) { w2##S = wp_[2]; w3##S = wp_[3]; }                         \
    }

#define STAGE(S) {                                                               \
        uint4 h0, h1, h2, h3;                                                    \
        h0 = g0##S; h1 = g1##S; h2 = g2##S; h3 = g3##S;                          \
        if (NORM) {                                                              \
            h0 = norm8(h0, na, nc); h1 = norm8(h1, na, nc);                      \
            h2 = norm8(h2, na, nc); h3 = norm8(h3, na, nc);                      \
        }                                                                        \
        *(uint4*)&gt[gr * 64 + (((gh << 2) | 0) ^ gswz) * 8] = h0;               \
        *(uint4*)&gt[gr * 64 + (((gh << 2) | 1) ^ gswz) * 8] = h1;               \
        *(uint4*)&gt[gr * 64 + (((gh << 2) | 2) ^ gswz) * 8] = h2;               \
        *(uint4*)&gt[gr * 64 + (((gh << 2) | 3) ^ gswz) * 8] = h3;               \
        *(uint4*)&wt[wr * 64 + ((wseg * NW + 0) ^ wswz) * 8] = w0##S;            \
        *(uint4*)&wt[wr * 64 + ((wseg * NW + 1) ^ wswz) * 8] = w1##S;            \
        if (NW == 4) {                                                           \
            *(uint4*)&wt[wr * 64 + ((wseg * NW + 2) ^ wswz) * 8] = w2##S;        \
            *(uint4*)&wt[wr * 64 + ((wseg * NW + 3) ^ wswz) * 8] = w3##S;        \
        }                                                                        \
    }

    const int nChunks = K >> 6;      // conv1:3, conv3:6
    LOADC(A, 0);
    if (nChunks > 1) LOADC(B, 1);
    int kc = 0;
    for (; kc + 2 <= nChunks; kc += 2) {
        if (kc) __syncthreads();              // prior chunk's LDS readers done
        STAGE(A);                             // waits set-A loads only
        if (kc + 2 < nChunks) LOADC(A, kc + 2);
        __syncthreads();
        mfma_step<MT, WM>(wt, gt, acc, wo, wn, quad, l15, blkid);
        __syncthreads();
        STAGE(B);
        if (kc + 3 < nChunks) LOADC(B, kc + 3);
        __syncthreads();
        mfma_step<MT, WM>(wt, gt, acc, wo, wn, quad, l15, blkid);
    }
    if (kc < nChunks) {                       // odd tail (conv1: chunk 2 in set A)
        __syncthreads();
        STAGE(A);
        __syncthreads();
        mfma_step<MT, WM>(wt, gt, acc, wo, wn, quad, l15, blkid);
    }
#undef LOADC
#undef STAGE

    // epilogue: bias, zero col 0, store (unless POOL), fused stats, fused max-pool
    float lsum = 0.f, lsq = 0.f;
#pragma unroll
    for (int i = 0; i < MT; i++) {
        const int ob = o0 + wo * WM + i * 16 + quad * 4;
        const float4 bv = *(const float4*)(bias + ob);
        float mx0 = -1e30f, mx1 = -1e30f, mx2 = -1e30f, mx3 = -1e30f;
#pragma unroll
        for (int t = 0; t < 4; t++) {
            const int n = nt0 + wn * 64 + t * 16 + l15;
            float v0 = acc[i][t][0] + bv.x;
            float v1 = acc[i][t][1] + bv.y;
            float v2 = acc[i][t][2] + bv.z;
            float v3 = acc[i][t][3] + bv.w;
            if (n == 0) { v0 = v1 = v2 = v3 = 0.f; }
            lsum += v0 + v1 + v2 + v3;
            lsq  += v0 * v0 + v1 * v1 + v2 * v2 + v3 * v3;
            if (POOL) {
                mx0 = fmaxf(mx0, v0); mx1 = fmaxf(mx1, v1);
                mx2 = fmaxf(mx2, v2); mx3 = fmaxf(mx3, v3);
            } else if (FP8OUT) {
                int r = __builtin_amdgcn_cvt_pk_fp8_f32(v0, v1, 0, false);
                r = __builtin_amdgcn_cvt_pk_fp8_f32(v2, v3, r, true);
                *(unsigned int*)&((unsigned char*)out)[((size_t)b * 1024 + n) * O + ob] =
                    (unsigned int)r;
            } else {
                uint2 pk;
                pk.x = pack_bf16_pair(v0, v1);
                pk.y = pack_bf16_pair(v2, v3);
                *(uint2*)&((unsigned short*)out)[((size_t)b * 1024 + n) * O + ob] = pk;
            }
        }
        if (POOL) {
#pragma unroll
            for (int off = 1; off < 16; off <<= 1) {
                mx0 = fmaxf(mx0, __shfl_xor(mx0, off));
                mx1 = fmaxf(mx1, __shfl_xor(mx1, off));
                mx2 = fmaxf(mx2, __shfl_xor(mx2, off));
                mx3 = fmaxf(mx3, __shfl_xor(mx3, off));
            }
            if (l15 == 0) {
                atomicMaxF(&pmax[(size_t)b * 64 + ob + 0], mx0);
                atomicMaxF(&pmax[(size_t)b * 64 + ob + 1], mx1);
                atomicMaxF(&pmax[(size_t)b * 64 + ob + 2], mx2);
                atomicMaxF(&pmax[(size_t)b * 64 + ob + 3], mx3);
            }
        }
    }
#pragma unroll
    for (int off = 32; off > 0; off >>= 1) {
        lsum += __shfl_down(lsum, off);
        lsq  += __shfl_down(lsq, off);
    }
    float* red = (float*)wt;  // wt dead after K-loop
    if (lane == 0) { red[wave] = lsum; red[4 + wave] = lsq; }
    __syncthreads();
    if (tid == 0) {
        atomicAdd(&sums[2 * b + 0], red[0] + red[1] + red[2] + red[3]);
        atomicAdd(&sums[2 * b + 1], red[4] + red[5] + red[6] + red[7]);
    }
}

// R12: conv2 as pure-copy-stage fp8 x fp8 MFMA. Inputs pre-normalized by
// norm_act_fp8; weights pre-quantized e4m3. Chunk = 128 k-elems (6 chunks,
// half the barriers of the bf16 version). Same LDS geometry as the verified
// bf16 path (128 B rows, 8x16B granules, XOR-by-row&7 swizzle; measured 0
// bank conflicts). fp8 16x16x32 fragment: 8 elems/lane, k = 8*qb, row = l15.
__global__ __launch_bounds__(256, 2) void conv2_fp8(
    const unsigned char* __restrict__ a1,    // [nB][1024][256] fp8, normalized
    const int* __restrict__ idxA,
    const int* __restrict__ idxB,
    const unsigned char* __restrict__ wq8,   // [128][768] fp8 e4m3
    const float* __restrict__ bias,          // [128] f32
    unsigned short* __restrict__ out,        // [nB][1024][128] bf16
    float* __restrict__ sums)                // [nB][2]
{
    const int b   = blockIdx.x;
    const int nt0 = blockIdx.z << 7;
    const int tid = threadIdx.x;
    const int lane = tid & 63, wave = tid >> 6;
    const int wo = wave & 1, wn = wave >> 1;
    const int quad = lane >> 4, l15 = lane & 15;
    const int blkid = lane & 7;

    __shared__ __align__(16) unsigned char wt8[128 * 128];
    __shared__ __align__(16) unsigned char gt8[128 * 128];

    f32x4 acc[4][4];
#pragma unroll
    for (int i = 0; i < 4; i++)
#pragma unroll
        for (int t = 0; t < 4; t++) acc[i][t] = (f32x4){0.f, 0.f, 0.f, 0.f};

    const unsigned char* xb = a1 + (((size_t)b) << 10) * 256;
    const int* idxb = (b >= 128 ? idxB : idxA) + (size_t)(b & 127) * 3069;

    const int gr = tid >> 1, gh = tid & 1;   // row, 64B-half (same for gt and wt)
    int si0, si1, si2;
    {
        int n = nt0 + gr;
        int t0 = (n == 0) ? 0 : (n - 1);
        si0 = idxb[3 * t0]; si1 = idxb[3 * t0 + 1]; si2 = idxb[3 * t0 + 2];
    }
    const unsigned char* wrow = wq8 + (size_t)gr * 768 + gh * 64;
    const int swz = gr & 7;

    uint4 g0A, g1A, g2A, g3A, w0A, w1A, w2A, w3A;
    uint4 g0B, g1B, g2B, g3B, w0B, w1B, w2B, w3B;

#define LOADC2(S, KC) {                                                          \
        const int j_  = (KC) >> 1;                                               \
        const int c0_ = ((KC) & 1) << 7;                                         \
        const int src_ = (j_ == 0) ? si0 : ((j_ == 1) ? si1 : si2);              \
        const uint4* gp_ = (const uint4*)(xb + (size_t)src_ * 256 + c0_ + gh * 64); \
        g0##S = gp_[0]; g1##S = gp_[1]; g2##S = gp_[2]; g3##S = gp_[3];          \
        const uint4* wp_ = (const uint4*)(wrow + (KC) * 128);                    \
        w0##S = wp_[0]; w1##S = wp_[1]; w2##S = wp_[2]; w3##S = wp_[3];          \
    }

#define STAGE2(S) {                                                              \
        *(uint4*)&gt8[gr * 128 + (((gh << 2) | 0) ^ swz) * 16] = g0##S;          \
        *(uint4*)&gt8[gr * 128 + (((gh << 2) | 1) ^ swz) * 16] = g1##S;          \
        *(uint4*)&gt8[gr * 128 + (((gh << 2) | 2) ^ swz) * 16] = g2##S;          \
        *(uint4*)&gt8[gr * 128 + (((gh << 2) | 3) ^ swz) * 16] = g3##S;          \
        *(uint4*)&wt8[gr * 128 + (((gh << 2) | 0) ^ swz) * 16] = w0##S;          \
        *(uint4*)&wt8[gr * 128 + (((gh << 2) | 1) ^ swz) * 16] = w1##S;          \
        *(uint4*)&wt8[gr * 128 + (((gh << 2) | 2) ^ swz) * 16] = w2##S;          \
        *(uint4*)&wt8[gr * 128 + (((gh << 2) | 3) ^ swz) * 16] = w3##S;          \
    }

#define MFMA_STEP2 {                                                             \
        _Pragma("unroll")                                                        \
        for (int st = 0; st < 4; ++st) {                                         \
            long af0, af1, af2, af3, bf0, bf1, bf2, bf3;                         \
            const int qb = st * 4 + quad;                                        \
            const int cg = qb >> 1, ch = (qb & 1) << 3;                          \
            {                                                                    \
                const int r0 = wo * 64 + 0 * 16 + l15;                           \
                af0 = *(const long*)&wt8[r0 * 128 + ((cg ^ blkid) << 4) + ch];   \
                const int r1 = wo * 64 + 1 * 16 + l15;                           \
                af1 = *(const long*)&wt8[r1 * 128 + ((cg ^ blkid) << 4) + ch];   \
                const int r2 = wo * 64 + 2 * 16 + l15;                           \
                af2 = *(const long*)&wt8[r2 * 128 + ((cg ^ blkid) << 4) + ch];   \
                const int r3 = wo * 64 + 3 * 16 + l15;                           \
                af3 = *(const long*)&wt8[r3 * 128 + ((cg ^ blkid) << 4) + ch];   \
                const int n0 = wn * 64 + 0 * 16 + l15;                           \
                bf0 = *(const long*)&gt8[n0 * 128 + ((cg ^ blkid) << 4) + ch];   \
                const int n1 = wn * 64 + 1 * 16 + l15;                           \
                bf1 = *(const long*)&gt8[n1 * 128 + ((cg ^ blkid) << 4) + ch];   \
                const int n2 = wn * 64 + 2 * 16 + l15;                           \
                bf2 = *(const long*)&gt8[n2 * 128 + ((cg ^ blkid) << 4) + ch];   \
                const int n3 = wn * 64 + 3 * 16 + l15;                           \
                bf3 = *(const long*)&gt8[n3 * 128 + ((cg ^ blkid) << 4) + ch];   \
            }                                                                    \
            acc[0][0] = __builtin_amdgcn_mfma_f32_16x16x32_fp8_fp8(af0, bf0, acc[0][0], 0, 0, 0); \
            acc[0][1] = __builtin_amdgcn_mfma_f32_16x16x32_fp8_fp8(af0, bf1, acc[0][1], 0, 0, 0); \
            acc[0][2] = __builtin_amdgcn_mfma_f32_16x16x32_fp8_fp8(af0, bf2, acc[0][2], 0, 0, 0); \
            acc[0][3] = __builtin_amdgcn_mfma_f32_16x16x32_fp8_fp8(af0, bf3, acc[0][3], 0, 0, 0); \
            acc[1][0] = __builtin_amdgcn_mfma_f32_16x16x32_fp8_fp8(af1, bf0, acc[1][0], 0, 0, 0); \
            acc[1][1] = __builtin_amdgcn_mfma_f32_16x16x32_fp8_fp8(af1, bf1, acc[1][1], 0, 0, 0); \
            acc[1][2] = __builtin_amdgcn_mfma_f32_16x16x32_fp8_fp8(af1, bf2, acc[1][2], 0, 0, 0); \
            acc[1][3] = __builtin_amdgcn_mfma_f32_16x16x32_fp8_fp8(af1, bf3, acc[1][3], 0, 0, 0); \
            acc[2][0] = __builtin_amdgcn_mfma_f32_16x16x32_fp8_fp8(af2, bf0, acc[2][0], 0, 0, 0); \
            acc[2][1] = __builtin_amdgcn_mfma_f32_16x16x32_fp8_fp8(af2, bf1, acc[2][1], 0, 0, 0); \
            acc[2][2] = __builtin_amdgcn_mfma_f32_16x16x32_fp8_fp8(af2, bf2, acc[2][2], 0, 0, 0); \
            acc[2][3] = __builtin_amdgcn_mfma_f32_16x16x32_fp8_fp8(af2, bf3, acc[2][3], 0, 0, 0); \
            acc[3][0] = __builtin_amdgcn_mfma_f32_16x16x32_fp8_fp8(af3, bf0, acc[3][0], 0, 0, 0); \
            acc[3][1] = __builtin_amdgcn_mfma_f32_16x16x32_fp8_fp8(af3, bf1, acc[3][1], 0, 0, 0); \
            acc[3][2] = __builtin_amdgcn_mfma_f32_16x16x32_fp8_fp8(af3, bf2, acc[3][2], 0, 0, 0); \
            acc[3][3] = __builtin_amdgcn_mfma_f32_16x16x32_fp8_fp8(af3, bf3, acc[3][3], 0, 0, 0); \
        }                                                                        \
    }

    LOADC2(A, 0);
    LOADC2(B, 1);
    int kc = 0;
    for (; kc + 2 <= 6; kc += 2) {
        if (kc) __syncthreads();
        STAGE2(A);
        if (kc + 2 < 6) LOADC2(A, kc + 2);
        __syncthreads();
        MFMA_STEP2;
        __syncthreads();
        STAGE2(B);
        if (kc + 3 < 6) LOADC2(B, kc + 3);
        __syncthreads();
        MFMA_STEP2;
    }
#undef LOADC2
#undef STAGE2
#undef MFMA_STEP2

    float lsum = 0.f, lsq = 0.f;
#pragma unroll
    for (int i = 0; i < 4; i++) {
        const int ob = wo * 64 + i * 16 + quad * 4;
        const float4 bv = *(const float4*)(bias + ob);
#pragma unroll
        for (int t = 0; t < 4; t++) {
            const int n = nt0 + wn * 64 + t * 16 + l15;
            float v0 = acc[i][t][0] + bv.x;
            float v1 = acc[i][t][1] + bv.y;
            float v2 = acc[i][t][2] + bv.z;
            float v3 = acc[i][t][3] + bv.w;
            if (n == 0) { v0 = v1 = v2 = v3 = 0.f; }
            lsum += v0 + v1 + v2 + v3;
            lsq  += v0 * v0 + v1 * v1 + v2 * v2 + v3 * v3;
            uint2 pk;
            pk.x = pack_bf16_pair(v0, v1);
            pk.y = pack_bf16_pair(v2, v3);
            *(uint2*)&out[((size_t)b * 1024 + n) * 128 + ob] = pk;
        }
    }
#pragma unroll
    for (int off = 32; off > 0; off >>= 1) {
        lsum += __shfl_down(lsum, off);
        lsq  += __shfl_down(lsq, off);
    }
    float* red = (float*)wt8;  // wt dead after K-loop
    if (lane == 0) { red[wave] = lsum; red[4 + wave] = lsq; }
    __syncthreads();
    if (tid == 0) {
        atomicAdd(&sums[2 * b + 0], red[0] + red[1] + red[2] + red[3]);
        atomicAdd(&sums[2 * b + 1], red[4] + red[5] + red[6] + red[7]);
    }
}

// pooled max -> normalize -> fc1+lrelu -> fc2
__global__ __launch_bounds__(64) void fc_head(
    const float* __restrict__ pmax, const float* __restrict__ sums3, float count,
    const float* __restrict__ w_fc1, const float* __restrict__ b_fc1,
    const float* __restrict__ w_fc2, const float* __restrict__ b_fc2,
    float* __restrict__ y)
{
    const int b = blockIdx.x, t = threadIdx.x;
    __shared__ float pooled[64];
    __shared__ float hid[32];
    float2 s = stats_from(sums3, b, count);
    pooled[t] = (pmax[(size_t)b * 64 + t] - s.x) * s.y;
    __syncthreads();
    if (t < 32) {
        float h = b_fc1[t];
#pragma unroll
        for (int c = 0; c < 64; c++) h += pooled[c] * w_fc1[t * 64 + c];
        hid[t] = LRELU(h);
    }
    __syncthreads();
    if (t == 0) {
        float v = b_fc2[0];
#pragma unroll
        for (int c = 0; c < 32; c++) v += hid[c] * w_fc2[c];
        y[b] = v;
    }
}

__global__ void sigmoid_diff(const float* __restrict__ y1,
                             const float* __restrict__ y2,
                             float* __restrict__ out)
{
    int b = threadIdx.x;
    if (b < 128) out[b] = 1.0f / (1.0f + expf(-(y1[b] - y2[b])));
}

extern "C" void kernel_launch(void* const* d_in, const int* in_sizes, int n_in,
                              void* d_out, int out_size, void* d_ws, size_t ws_size,
                              hipStream_t stream)
{
    const float* data1 = (const float*)d_in[0];
    const int*   idx1  = (const int*)d_in[1];
    const float* data2 = (const float*)d_in[2];
    const int*   idx2  = (const int*)d_in[3];
    const float* w1 = (const float*)d_in[4];
    const float* b1 = (const float*)d_in[5];
    const float* w2 = (const float*)d_in[6];
    const float* b2 = (const float*)d_in[7];
    const float* w3 = (const float*)d_in[8];
    const float* b3 = (const float*)d_in[9];
    const float* wfc1 = (const float*)d_in[10];
    const float* bfc1 = (const float*)d_in[11];
    const float* wfc2 = (const float*)d_in[12];
    const float* bfc2 = (const float*)d_in[13];

    // a1 is fp8 (1B/elem); xT and a2 stay bf16
    const size_t needM = (size_t)256 * 1024 * (64 * 2 + 256 * 1 + 128 * 2) + 768 * 1024;
    const bool merged = ws_size >= needM;
    const int nB = merged ? 256 : 128;
    const size_t szXT = (size_t)nB * 1024 * 64 * 2;
    const size_t szA1 = (size_t)nB * 1024 * 256;       // fp8
    const size_t szA2 = (size_t)nB * 1024 * 128 * 2;

    char* ws = (char*)d_ws;
    unsigned short* xT = (unsigned short*)ws;
    unsigned char*  a1 = (unsigned char*)(ws + szXT);
    unsigned short* a2 = (unsigned short*)(ws + szXT + szA1);
    char* tail = ws + szXT + szA1 + szA2;
    unsigned short* wq1 = (unsigned short*)tail;                 // 96 KB
    unsigned char*  wq2f8 = (unsigned char*)(tail + 128 * 1024); // 96 KB (fp8)
    unsigned short* wq3 = (unsigned short*)(tail + 384 * 1024);  // 48 KB
    float* sums = (float*)(tail + 448 * 1024);                   // 3*nB*2 f32
    float* pmax = (float*)(tail + 512 * 1024);                   // nB*64 f32
    float* yv   = (float*)(tail + 640 * 1024);                   // 256 f32

    prep_weights<<<96, 256, 0, stream>>>(w1, wq1, 256, 64);
    prep_weights_fp8<<<96, 256, 0, stream>>>(w2, wq2f8, 128, 256);
    prep_weights<<<96, 256, 0, stream>>>(w3, wq3, 64, 128);

    const int nIter = merged ? 1 : 2;
    for (int t = 0; t < nIter; ++t) {
        const float* dA = (merged || t == 0) ? data1 : data2;
        const float* dB = merged ? data2 : dA;
        const int* iA = (merged || t == 0) ? idx1 : idx2;
        const int* iB = merged ? idx2 : iA;
        float* s1 = sums;
        float* s2 = sums + nB * 2;
        float* s3 = sums + nB * 4;

        hipMemsetAsync(sums, 0, 3 * (size_t)nB * 2 * sizeof(float), stream);
        hipMemsetAsync(pmax, 0xFF, (size_t)nB * 64 * sizeof(float), stream);

        transpose_in<<<dim3(16, nB), 256, 0, stream>>>(dA, dB, xT);

        // conv1: bf16 in, fp8 out (halves the 134MB streaming write)
        conv_mfma<128, false, false, false, true><<<dim3(nB, 2, 8), 256, 0, stream>>>(
            xT, iA, iB, wq1, b1, a1, s1, nullptr, nullptr, 0.0f, 64, 6, 256, 192);

        // R12: normalize+lrelu a1 ONCE (in place), then pure-copy fp8 MFMA conv2
        norm_act_fp8<<<dim3(16, nB), 256, 0, stream>>>(a1, s1, 256.0f * 1024.0f);

        conv2_fp8<<<dim3(nB, 1, 8), 256, 0, stream>>>(
            a1, iA, iB, wq2f8, b2, a2, s2);

        conv_mfma<64, true, true, false, false><<<dim3(nB, 1, 8), 256, 0, stream>>>(
            a2, iA, iB, wq3, b3, nullptr, s3, pmax, s2, 128.0f * 1024.0f, 128, 7, 64, 384);

        fc_head<<<nB, 64, 0, stream>>>(pmax, s3, 64.0f * 1024.0f,
                                       wfc1, bfc1, wfc2, bfc2,
                                       yv + (merged ? 0 : t * 128));
    }
    sigmoid_diff<<<1, 128, 0, stream>>>(yv, yv + 128, (float*)d_out);
}

// Round 3
// 318.126 us; speedup vs baseline: 1.0230x; 1.0187x over previous
//
#include <hip/hip_runtime.h>
#include <math.h>

typedef __attribute__((ext_vector_type(8))) short short8;
typedef __attribute__((ext_vector_type(4))) float f32x4;
typedef __attribute__((ext_vector_type(2))) float f32x2;

#define LRELU(x) ((x) > 0.0f ? (x) : 0.01f * (x))

__device__ __forceinline__ float bf2f(unsigned short h) {
    return __uint_as_float(((unsigned int)h) << 16);
}
__device__ __forceinline__ unsigned short f2bf(float f) {
    unsigned int u = __float_as_uint(f);
    return (unsigned short)((u + 0x7FFFu + ((u >> 16) & 1u)) >> 16);
}
// round-half-up bf16 pair pack: ~5 VALU vs ~10 for RNE; <=0.5 ULP error
__device__ __forceinline__ unsigned int pack_bf16_pair(float lo, float hi) {
    unsigned int ul = __float_as_uint(lo) + 0x8000u;
    unsigned int uh = __float_as_uint(hi) + 0x8000u;
    return (ul >> 16) | (uh & 0xFFFF0000u);
}
__device__ __forceinline__ float2 stats_from(const float* sums, int b, float count) {
    float s = sums[2 * b], q = sums[2 * b + 1];
    float mean = s / count;
    float var = (q - s * s / count) / (count - 1.0f);  // ddof=1
    var = fmaxf(var, 0.0f);
    return make_float2(mean, 1.0f / (sqrtf(var) + 1e-5f));
}
// init pattern 0xFFFFFFFF (-NaN): positives via signed max, negatives via unsigned min
__device__ __forceinline__ void atomicMaxF(float* a, float v) {
    if (v >= 0.0f) atomicMax((int*)a, __float_as_int(v));
    else           atomicMin((unsigned int*)a, __float_as_uint(v));
}
// y = lrelu(x * a + c) on a packed bf16 pair, via packed-f32 (VOP3P) ops
__device__ __forceinline__ unsigned int norm_pair(unsigned int u, float a, float c) {
    f32x2 v;
    v.x = __uint_as_float(u << 16);
    v.y = __uint_as_float(u & 0xFFFF0000u);
    v = v * a + c;
    f32x2 m = v * 0.01f;
    v = __builtin_elementwise_max(v, m);
    return pack_bf16_pair(v.x, v.y);
}
__device__ __forceinline__ uint4 norm8(uint4 v, float a, float c) {
    v.x = norm_pair(v.x, a, c); v.y = norm_pair(v.y, a, c);
    v.z = norm_pair(v.z, a, c); v.w = norm_pair(v.w, a, c);
    return v;
}
// 4 fp8 e4m3 -> lrelu(x*a+c) -> 4 fp8 e4m3 (in-register, for the norm_act pass)
__device__ __forceinline__ unsigned int fp8x4_nact(unsigned int u, float a, float c) {
    f32x2 lo = __builtin_amdgcn_cvt_pk_f32_fp8(u, false);
    f32x2 hi = __builtin_amdgcn_cvt_pk_f32_fp8(u, true);
    lo = lo * a + c; hi = hi * a + c;
    f32x2 ml = lo * 0.01f, mh = hi * 0.01f;
    lo = __builtin_elementwise_max(lo, ml);
    hi = __builtin_elementwise_max(hi, mh);
    int r = __builtin_amdgcn_cvt_pk_fp8_f32(lo.x, lo.y, 0, false);
    r = __builtin_amdgcn_cvt_pk_fp8_f32(hi.x, hi.y, r, true);
    return (unsigned int)r;
}

// MFMA fragment block (bf16): LDS -> frags -> 2 k-stages of 16x16x32 bf16 MFMAs
template <int MT, int WM>
__device__ __forceinline__ void mfma_step(const unsigned short* wt, const unsigned short* gt,
                                          f32x4 (&acc)[MT][4],
                                          int wo, int wn, int quad, int l15, int blkid)
{
#pragma unroll
    for (int st = 0; st < 2; ++st) {
        short8 af[MT], bfv[4];
        const int qb = st * 4 + quad;
#pragma unroll
        for (int i = 0; i < MT; i++) {
            const int orow = wo * WM + i * 16 + l15;
            af[i] = *(const short8*)&wt[orow * 64 + ((qb ^ blkid) << 3)];
        }
#pragma unroll
        for (int t = 0; t < 4; t++) {
            const int nrow = wn * 64 + t * 16 + l15;
            bfv[t] = *(const short8*)&gt[nrow * 64 + ((qb ^ blkid) << 3)];
        }
#pragma unroll
        for (int i = 0; i < MT; i++)
#pragma unroll
            for (int t = 0; t < 4; t++)
                acc[i][t] = __builtin_amdgcn_mfma_f32_16x16x32_bf16(
                    af[i], bfv[t], acc[i][t], 0, 0, 0);
    }
}

// R13: single prep kernel (was 3 launches). w1/w3 -> bf16, w2 -> fp8 e4m3.
__global__ void prep_all(const float* __restrict__ w1, unsigned short* __restrict__ wq1,
                         const float* __restrict__ w2, unsigned char* __restrict__ wq2,
                         const float* __restrict__ w3, unsigned short* __restrict__ wq3)
{
    const int tid = blockIdx.x * blockDim.x + threadIdx.x;
    const int stride = gridDim.x * blockDim.x;
    // w1: O=256, Cin=64, K=192
    for (int i = tid; i < 256 * 192; i += stride) {
        int o = i / 192, kp = i - o * 192;
        int j = kp >> 6, c = kp & 63;
        wq1[i] = f2bf(w1[(o * 64 + c) * 3 + j]);
    }
    // w2 -> fp8: O=128, Cin=256, K=768 (4 consecutive k' share j since 4|256)
    for (int i = tid; i < (128 * 768) >> 2; i += stride) {
        const int e0 = i << 2;
        const int o = e0 / 768, kp0 = e0 - o * 768;
        const int j = kp0 >> 8, c0 = kp0 & 255;
        const float* src = &w2[(o * 256 + c0) * 3 + j];
        float f0 = src[0], f1 = src[3], f2 = src[6], f3 = src[9];
        int r = __builtin_amdgcn_cvt_pk_fp8_f32(f0, f1, 0, false);
        r = __builtin_amdgcn_cvt_pk_fp8_f32(f2, f3, r, true);
        *(unsigned int*)&wq2[e0] = (unsigned int)r;
    }
    // w3: O=64, Cin=128, K=384
    for (int i = tid; i < 64 * 384; i += stride) {
        int o = i / 384, kp = i - o * 384;
        int j = kp >> 7, c = kp & 127;
        wq3[i] = f2bf(w3[(o * 128 + c) * 3 + j]);
    }
}

// data [128][64][1024] f32 -> xT [nB][1024][64] bf16 (tower select on b>=128)
// R13: block (0,0) also re-inits sums/pmax (replaces 2 hipMemsetAsync dispatches;
// safe: all consumers are stream-ordered after this kernel).
__global__ __launch_bounds__(256) void transpose_in(const float* __restrict__ inA,
                                                    const float* __restrict__ inB,
                                                    unsigned short* __restrict__ xT,
                                                    float* __restrict__ sums,
                                                    unsigned int* __restrict__ pmax)
{
    const int b = blockIdx.y, n0 = blockIdx.x * 64;
    const float* in = (b >= 128 ? inB : inA) + ((size_t)(b & 127) * 64) * 1024;
    const int tid = threadIdx.x;
    if (blockIdx.x == 0 && blockIdx.y == 0) {
        const int nBv = gridDim.y;
        for (int i = tid; i < 3 * nBv * 2; i += 256) sums[i] = 0.0f;
        for (int i = tid; i < nBv * 64; i += 256) pmax[i] = 0xFFFFFFFFu;
    }
    __shared__ float tile[64][65];
    const int nn = tid & 63, cw = tid >> 6;
#pragma unroll
    for (int i = 0; i < 16; i++) {
        int c = i * 4 + cw;
        tile[c][nn] = in[(size_t)c * 1024 + n0 + nn];
    }
    __syncthreads();
    const int n = tid >> 2, cp = (tid & 3) * 16;
    unsigned int pk[8];
#pragma unroll
    for (int i = 0; i < 8; i++) {
        unsigned short lo = f2bf(tile[cp + 2 * i][n]);
        unsigned short hi = f2bf(tile[cp + 2 * i + 1][n]);
        pk[i] = (unsigned int)lo | ((unsigned int)hi << 16);
    }
    unsigned short* dst = xT + ((size_t)b * 1024 + n0 + n) * 64 + cp;
    uint4 v0 = {pk[0], pk[1], pk[2], pk[3]};
    uint4 v1 = {pk[4], pk[5], pk[6], pk[7]};
    *(uint4*)dst = v0;
    *(uint4*)(dst + 8) = v1;
}

// R12: apply lrelu(norm(.)) ONCE per a1 element (in place), instead of ~3x inside
// conv2's gather-amplified STAGE.
__global__ __launch_bounds__(256) void norm_act_fp8(unsigned char* __restrict__ a,
                                                    const float* __restrict__ sums,
                                                    float count)
{
    const int b = blockIdx.y;
    float2 st = stats_from(sums, b, count);
    const float na = st.y, nc = -st.x * st.y;
    uint4* p = (uint4*)(a + ((size_t)b << 18));          // 256 KB per b
    const int base = blockIdx.x * 256 + threadIdx.x;     // grid.x = 16 -> 4096 threads
#pragma unroll
    for (int it = 0; it < 4; ++it) {
        const int idx = base + it * 4096;                // 16384 uint4 per b
        uint4 v = p[idx];
        v.x = fp8x4_nact(v.x, na, nc);
        v.y = fp8x4_nact(v.y, na, nc);
        v.z = fp8x4_nact(v.z, na, nc);
        v.w = fp8x4_nact(v.w, na, nc);
        p[idx] = v;
    }
}

// MFMA gather-conv, register-staged 2-deep pipelined K-loop (named scalars only:
// local arrays fail SROA -> scratch, the R5-R7 600MB bug).
// R13: all convs are gather-LATENCY-bound at ~2 blocks/CU (R12 counters: HBM 17%,
// Mfma 14%, VALU 20%, occ 18%). Weights are L2-hot -> 1-deep transient staging
// inside STAGE (frees ~16 persistent VGPRs) + __launch_bounds__(256,3) targets
// 3 blocks/CU. Gathers stay 2-deep register-staged (no global_load_lds anywhere:
// it would force vmcnt(0) at every barrier and kill the register pipeline).
template <int BM, bool POOL, bool NORM, bool FP8IN, bool FP8OUT>
__global__ __launch_bounds__(256, 3) void conv_mfma(
    const void* __restrict__ xTv,            // [nB][1024][Cin] bf16 or fp8 (raw)
    const int* __restrict__ idxA,            // [128][3069]
    const int* __restrict__ idxB,
    const unsigned short* __restrict__ wq,   // [O][K] bf16 (k'=j*Cin+c)
    const float* __restrict__ bias,          // [O] f32
    void* __restrict__ out,                  // [nB][1024][O] bf16/fp8 (unused if POOL)
    float* __restrict__ sums,                // [nB][2] accum (this layer's raw stats)
    float* __restrict__ pmax,                // [nB][64] (POOL only)
    const float* __restrict__ normSums,      // [nB][2] prev-layer stats (NORM only)
    float normCount, int Cin, int cinShift, int O, int K)
{
    constexpr int WM = BM / 2, MT = WM / 16;
    constexpr int NW = (BM == 128) ? 4 : 2;      // 16B packets of wt per thread
    const int b   = blockIdx.x;
    const int o0  = blockIdx.y * BM;
    const int nt0 = blockIdx.z << 7;
    const int tid = threadIdx.x;
    const int lane = tid & 63, wave = tid >> 6;
    const int wo = wave & 1, wn = wave >> 1;
    const int quad = lane >> 4, l15 = lane & 15;
    const int blkid = lane & 7;

    __shared__ __align__(16) unsigned short wt[BM * 64];
    __shared__ __align__(16) unsigned short gt[128 * 64];

    f32x4 acc[MT][4];
#pragma unroll
    for (int i = 0; i < MT; i++)
#pragma unroll
        for (int t = 0; t < 4; t++) acc[i][t] = (f32x4){0.f, 0.f, 0.f, 0.f};

    const unsigned short* xTb16 = (const unsigned short*)xTv + (((size_t)b) << 10) * (size_t)Cin;
    const unsigned char*  xTb8  = (const unsigned char*)xTv  + (((size_t)b) << 10) * (size_t)Cin;
    const int* idxb = (b >= 128 ? idxB : idxA) + (size_t)(b & 127) * 3069;

    float na = 1.0f, nc = 0.0f;
    if (NORM) {
        float2 st = stats_from(normSums, b, normCount);
        na = st.y; nc = -st.x * st.y;
    }

    // --- staging mapping ---
    const int gr = tid >> 1, gh = tid & 1;       // gt row (n), 32-channel half
    int s0, s1, s2;
    {
        int n = nt0 + gr;
        int t0 = (n == 0) ? 0 : (n - 1);         // n==0 row is garbage, zeroed later
        s0 = idxb[3 * t0]; s1 = idxb[3 * t0 + 1]; s2 = idxb[3 * t0 + 2];
    }
    const int wr   = (BM == 128) ? (tid >> 1) : (tid >> 2);  // wt row (o)
    const int wseg = (BM == 128) ? (tid & 1) : (tid & 3);    // segment of NW packets
    const unsigned short* wrow = wq + (size_t)(o0 + wr) * K + wseg * (NW * 8);
    const int gswz = gr & 7, wswz = wr & 7;

    // two independent gather staging sets (pipeline depth 2), all named scalars
    uint4 g0A, g1A, g2A, g3A;
    uint4 g0B, g1B, g2B, g3B;

#define LOADC(S, KC) {                                                           \
        const int k64_ = (KC) << 6;                                              \
        const int j_   = k64_ >> cinShift;                                       \
        const int c0_  = k64_ & (Cin - 1);                                       \
        const int src_ = (j_ == 0) ? s0 : ((j_ == 1) ? s1 : s2);                 \
        if (FP8IN) {                                                             \
            const uint4* gp_ = (const uint4*)(xTb8 + (size_t)src_ * Cin + c0_ + gh * 32); \
            g0##S = gp_[0]; g1##S = gp_[1];                                      \
        } else {                                                                 \
            const uint4* gp_ = (const uint4*)(xTb16 + (size_t)src_ * Cin + c0_ + gh * 32); \
            g0##S = gp_[0]; g1##S = gp_[1]; g2##S = gp_[2]; g3##S = gp_[3];      \
        }                                                                        \
    }

// weights loaded 1-deep here (L2-hot; latency hidden under gt norm/pack+writes)
#define STAGE(S, KC) {                                                           \
        const uint4* wp_ = (const uint4*)(wrow + ((KC) << 6));                   \
        uint4 wv0 = wp_[0], wv1 = wp_[1], wv2, wv3;                              \
        if (NW == 4) { wv2 = wp_[2]; wv3 = wp_[3]; }                             \
        uint4 h0, h1, h2, h3;                                                    \
        h0 = g0##S; h1 = g1##S; h2 = g2##S; h3 = g3##S;                          \
        if (NORM) {                                                              \
            h0 = norm8(h0, na, nc); h1 = norm8(h1, na, nc);                      \
            h2 = norm8(h2, na, nc); h3 = norm8(h3, na, nc);                      \
        }                                                                        \
        *(uint4*)&gt[gr * 64 + (((gh << 2) | 0) ^ gswz) * 8] = h0;               \
        *(uint4*)&gt[gr * 64 + (((gh << 2) | 1) ^ gswz) * 8] = h1;               \
        *(uint4*)&gt[gr * 64 + (((gh << 2) | 2) ^ gswz) * 8] = h2;               \
        *(uint4*)&gt[gr * 64 + (((gh << 2) | 3) ^ gswz) * 8] = h3;               \
        *(uint4*)&wt[wr * 64 + ((wseg * NW + 0) ^ wswz) * 8] = wv0;              \
        *(uint4*)&wt[wr * 64 + ((wseg * NW + 1) ^ wswz) * 8] = wv1;              \
        if (NW == 4) {                                                           \
            *(uint4*)&wt[wr * 64 + ((wseg * NW + 2) ^ wswz) * 8] = wv2;          \
            *(uint4*)&wt[wr * 64 + ((wseg * NW + 3) ^ wswz) * 8] = wv3;          \
        }                                                                        \
    }

    const int nChunks = K >> 6;      // conv1:3, conv3:6
    LOADC(A, 0);
    if (nChunks > 1) LOADC(B, 1);
    int kc = 0;
    for (; kc + 2 <= nChunks; kc += 2) {
        if (kc) __syncthreads();              // prior chunk's LDS readers done
        STAGE(A, kc);                         // waits set-A gather loads only
        if (kc + 2 < nChunks) LOADC(A, kc + 2);
        __syncthreads();
        mfma_step<MT, WM>(wt, gt, acc, wo, wn, quad, l15, blkid);
        __syncthreads();
        STAGE(B, kc + 1);
        if (kc + 3 < nChunks) LOADC(B, kc + 3);
        __syncthreads();
        mfma_step<MT, WM>(wt, gt, acc, wo, wn, quad, l15, blkid);
    }
    if (kc < nChunks) {                       // odd tail (conv1: chunk 2 in set A)
        __syncthreads();
        STAGE(A, kc);
        __syncthreads();
        mfma_step<MT, WM>(wt, gt, acc, wo, wn, quad, l15, blkid);
    }
#undef LOADC
#undef STAGE

    // epilogue: bias, zero col 0, store (unless POOL), fused stats, fused max-pool
    float lsum = 0.f, lsq = 0.f;
#pragma unroll
    for (int i = 0; i < MT; i++) {
        const int ob = o0 + wo * WM + i * 16 + quad * 4;
        const float4 bv = *(const float4*)(bias + ob);
        float mx0 = -1e30f, mx1 = -1e30f, mx2 = -1e30f, mx3 = -1e30f;
#pragma unroll
        for (int t = 0; t < 4; t++) {
            const int n = nt0 + wn * 64 + t * 16 + l15;
            float v0 = acc[i][t][0] + bv.x;
            float v1 = acc[i][t][1] + bv.y;
            float v2 = acc[i][t][2] + bv.z;
            float v3 = acc[i][t][3] + bv.w;
            if (n == 0) { v0 = v1 = v2 = v3 = 0.f; }
            lsum += v0 + v1 + v2 + v3;
            lsq  += v0 * v0 + v1 * v1 + v2 * v2 + v3 * v3;
            if (POOL) {
                mx0 = fmaxf(mx0, v0); mx1 = fmaxf(mx1, v1);
                mx2 = fmaxf(mx2, v2); mx3 = fmaxf(mx3, v3);
            } else if (FP8OUT) {
                int r = __builtin_amdgcn_cvt_pk_fp8_f32(v0, v1, 0, false);
                r = __builtin_amdgcn_cvt_pk_fp8_f32(v2, v3, r, true);
                *(unsigned int*)&((unsigned char*)out)[((size_t)b * 1024 + n) * O + ob] =
                    (unsigned int)r;
            } else {
                uint2 pk;
                pk.x = pack_bf16_pair(v0, v1);
                pk.y = pack_bf16_pair(v2, v3);
                *(uint2*)&((unsigned short*)out)[((size_t)b * 1024 + n) * O + ob] = pk;
            }
        }
        if (POOL) {
#pragma unroll
            for (int off = 1; off < 16; off <<= 1) {
                mx0 = fmaxf(mx0, __shfl_xor(mx0, off));
                mx1 = fmaxf(mx1, __shfl_xor(mx1, off));
                mx2 = fmaxf(mx2, __shfl_xor(mx2, off));
                mx3 = fmaxf(mx3, __shfl_xor(mx3, off));
            }
            if (l15 == 0) {
                atomicMaxF(&pmax[(size_t)b * 64 + ob + 0], mx0);
                atomicMaxF(&pmax[(size_t)b * 64 + ob + 1], mx1);
                atomicMaxF(&pmax[(size_t)b * 64 + ob + 2], mx2);
                atomicMaxF(&pmax[(size_t)b * 64 + ob + 3], mx3);
            }
        }
    }
#pragma unroll
    for (int off = 32; off > 0; off >>= 1) {
        lsum += __shfl_down(lsum, off);
        lsq  += __shfl_down(lsq, off);
    }
    float* red = (float*)wt;  // wt dead after K-loop
    if (lane == 0) { red[wave] = lsum; red[4 + wave] = lsq; }
    __syncthreads();
    if (tid == 0) {
        atomicAdd(&sums[2 * b + 0], red[0] + red[1] + red[2] + red[3]);
        atomicAdd(&sums[2 * b + 1], red[4] + red[5] + red[6] + red[7]);
    }
}

// R12: conv2 as pure-copy-stage fp8 x fp8 MFMA. Inputs pre-normalized by
// norm_act_fp8; weights pre-quantized e4m3. R13: weights 1-deep in STAGE2,
// __launch_bounds__(256,3) (same occupancy rationale as conv_mfma).
__global__ __launch_bounds__(256, 3) void conv2_fp8(
    const unsigned char* __restrict__ a1,    // [nB][1024][256] fp8, normalized
    const int* __restrict__ idxA,
    const int* __restrict__ idxB,
    const unsigned char* __restrict__ wq8,   // [128][768] fp8 e4m3
    const float* __restrict__ bias,          // [128] f32
    unsigned short* __restrict__ out,        // [nB][1024][128] bf16
    float* __restrict__ sums)                // [nB][2]
{
    const int b   = blockIdx.x;
    const int nt0 = blockIdx.z << 7;
    const int tid = threadIdx.x;
    const int lane = tid & 63, wave = tid >> 6;
    const int wo = wave & 1, wn = wave >> 1;
    const int quad = lane >> 4, l15 = lane & 15;
    const int blkid = lane & 7;

    __shared__ __align__(16) unsigned char wt8[128 * 128];
    __shared__ __align__(16) unsigned char gt8[128 * 128];

    f32x4 acc[4][4];
#pragma unroll
    for (int i = 0; i < 4; i++)
#pragma unroll
        for (int t = 0; t < 4; t++) acc[i][t] = (f32x4){0.f, 0.f, 0.f, 0.f};

    const unsigned char* xb = a1 + (((size_t)b) << 10) * 256;
    const int* idxb = (b >= 128 ? idxB : idxA) + (size_t)(b & 127) * 3069;

    const int gr = tid >> 1, gh = tid & 1;   // row, 64B-half (same for gt and wt)
    int si0, si1, si2;
    {
        int n = nt0 + gr;
        int t0 = (n == 0) ? 0 : (n - 1);
        si0 = idxb[3 * t0]; si1 = idxb[3 * t0 + 1]; si2 = idxb[3 * t0 + 2];
    }
    const unsigned char* wrow = wq8 + (size_t)gr * 768 + gh * 64;
    const int swz = gr & 7;

    uint4 g0A, g1A, g2A, g3A;
    uint4 g0B, g1B, g2B, g3B;

#define LOADC2(S, KC) {                                                          \
        const int j_  = (KC) >> 1;                                               \
        const int c0_ = ((KC) & 1) << 7;                                         \
        const int src_ = (j_ == 0) ? si0 : ((j_ == 1) ? si1 : si2);              \
        const uint4* gp_ = (const uint4*)(xb + (size_t)src_ * 256 + c0_ + gh * 64); \
        g0##S = gp_[0]; g1##S = gp_[1]; g2##S = gp_[2]; g3##S = gp_[3];          \
    }

#define STAGE2(S, KC) {                                                          \
        const uint4* wp_ = (const uint4*)(wrow + (KC) * 128);                    \
        uint4 wv0 = wp_[0], wv1 = wp_[1], wv2 = wp_[2], wv3 = wp_[3];            \
        *(uint4*)&gt8[gr * 128 + (((gh << 2) | 0) ^ swz) * 16] = g0##S;          \
        *(uint4*)&gt8[gr * 128 + (((gh << 2) | 1) ^ swz) * 16] = g1##S;          \
        *(uint4*)&gt8[gr * 128 + (((gh << 2) | 2) ^ swz) * 16] = g2##S;          \
        *(uint4*)&gt8[gr * 128 + (((gh << 2) | 3) ^ swz) * 16] = g3##S;          \
        *(uint4*)&wt8[gr * 128 + (((gh << 2) | 0) ^ swz) * 16] = wv0;            \
        *(uint4*)&wt8[gr * 128 + (((gh << 2) | 1) ^ swz) * 16] = wv1;            \
        *(uint4*)&wt8[gr * 128 + (((gh << 2) | 2) ^ swz) * 16] = wv2;            \
        *(uint4*)&wt8[gr * 128 + (((gh << 2) | 3) ^ swz) * 16] = wv3;            \
    }

#define MFMA_STEP2 {                                                             \
        _Pragma("unroll")                                                        \
        for (int st = 0; st < 4; ++st) {                                         \
            long af0, af1, af2, af3, bf0, bf1, bf2, bf3;                         \
            const int qb = st * 4 + quad;                                        \
            const int cg = qb >> 1, ch = (qb & 1) << 3;                          \
            {                                                                    \
                const int r0 = wo * 64 + 0 * 16 + l15;                           \
                af0 = *(const long*)&wt8[r0 * 128 + ((cg ^ blkid) << 4) + ch];   \
                const int r1 = wo * 64 + 1 * 16 + l15;                           \
                af1 = *(const long*)&wt8[r1 * 128 + ((cg ^ blkid) << 4) + ch];   \
                const int r2 = wo * 64 + 2 * 16 + l15;                           \
                af2 = *(const long*)&wt8[r2 * 128 + ((cg ^ blkid) << 4) + ch];   \
                const int r3 = wo * 64 + 3 * 16 + l15;                           \
                af3 = *(const long*)&wt8[r3 * 128 + ((cg ^ blkid) << 4) + ch];   \
                const int n0 = wn * 64 + 0 * 16 + l15;                           \
                bf0 = *(const long*)&gt8[n0 * 128 + ((cg ^ blkid) << 4) + ch];   \
                const int n1 = wn * 64 + 1 * 16 + l15;                           \
                bf1 = *(const long*)&gt8[n1 * 128 + ((cg ^ blkid) << 4) + ch];   \
                const int n2 = wn * 64 + 2 * 16 + l15;                           \
                bf2 = *(const long*)&gt8[n2 * 128 + ((cg ^ blkid) << 4) + ch];   \
                const int n3 = wn * 64 + 3 * 16 + l15;                           \
                bf3 = *(const long*)&gt8[n3 * 128 + ((cg ^ blkid) << 4) + ch];   \
            }                                                                    \
            acc[0][0] = __builtin_amdgcn_mfma_f32_16x16x32_fp8_fp8(af0, bf0, acc[0][0], 0, 0, 0); \
            acc[0][1] = __builtin_amdgcn_mfma_f32_16x16x32_fp8_fp8(af0, bf1, acc[0][1], 0, 0, 0); \
            acc[0][2] = __builtin_amdgcn_mfma_f32_16x16x32_fp8_fp8(af0, bf2, acc[0][2], 0, 0, 0); \
            acc[0][3] = __builtin_amdgcn_mfma_f32_16x16x32_fp8_fp8(af0, bf3, acc[0][3], 0, 0, 0); \
            acc[1][0] = __builtin_amdgcn_mfma_f32_16x16x32_fp8_fp8(af1, bf0, acc[1][0], 0, 0, 0); \
            acc[1][1] = __builtin_amdgcn_mfma_f32_16x16x32_fp8_fp8(af1, bf1, acc[1][1], 0, 0, 0); \
            acc[1][2] = __builtin_amdgcn_mfma_f32_16x16x32_fp8_fp8(af1, bf2, acc[1][2], 0, 0, 0); \
            acc[1][3] = __builtin_amdgcn_mfma_f32_16x16x32_fp8_fp8(af1, bf3, acc[1][3], 0, 0, 0); \
            acc[2][0] = __builtin_amdgcn_mfma_f32_16x16x32_fp8_fp8(af2, bf0, acc[2][0], 0, 0, 0); \
            acc[2][1] = __builtin_amdgcn_mfma_f32_16x16x32_fp8_fp8(af2, bf1, acc[2][1], 0, 0, 0); \
            acc[2][2] = __builtin_amdgcn_mfma_f32_16x16x32_fp8_fp8(af2, bf2, acc[2][2], 0, 0, 0); \
            acc[2][3] = __builtin_amdgcn_mfma_f32_16x16x32_fp8_fp8(af2, bf3, acc[2][3], 0, 0, 0); \
            acc[3][0] = __builtin_amdgcn_mfma_f32_16x16x32_fp8_fp8(af3, bf0, acc[3][0], 0, 0, 0); \
            acc[3][1] = __builtin_amdgcn_mfma_f32_16x16x32_fp8_fp8(af3, bf1, acc[3][1], 0, 0, 0); \
            acc[3][2] = __builtin_amdgcn_mfma_f32_16x16x32_fp8_fp8(af3, bf2, acc[3][2], 0, 0, 0); \
            acc[3][3] = __builtin_amdgcn_mfma_f32_16x16x32_fp8_fp8(af3, bf3, acc[3][3], 0, 0, 0); \
        }                                                                        \
    }

    LOADC2(A, 0);
    LOADC2(B, 1);
    int kc = 0;
    for (; kc + 2 <= 6; kc += 2) {
        if (kc) __syncthreads();
        STAGE2(A, kc);
        if (kc + 2 < 6) LOADC2(A, kc + 2);
        __syncthreads();
        MFMA_STEP2;
        __syncthreads();
        STAGE2(B, kc + 1);
        if (kc + 3 < 6) LOADC2(B, kc + 3);
        __syncthreads();
        MFMA_STEP2;
    }
#undef LOADC2
#undef STAGE2
#undef MFMA_STEP2

    float lsum = 0.f, lsq = 0.f;
#pragma unroll
    for (int i = 0; i < 4; i++) {
        const int ob = wo * 64 + i * 16 + quad * 4;
        const float4 bv = *(const float4*)(bias + ob);
#pragma unroll
        for (int t = 0; t < 4; t++) {
            const int n = nt0 + wn * 64 + t * 16 + l15;
            float v0 = acc[i][t][0] + bv.x;
            float v1 = acc[i][t][1] + bv.y;
            float v2 = acc[i][t][2] + bv.z;
            float v3 = acc[i][t][3] + bv.w;
            if (n == 0) { v0 = v1 = v2 = v3 = 0.f; }
            lsum += v0 + v1 + v2 + v3;
            lsq  += v0 * v0 + v1 * v1 + v2 * v2 + v3 * v3;
            uint2 pk;
            pk.x = pack_bf16_pair(v0, v1);
            pk.y = pack_bf16_pair(v2, v3);
            *(uint2*)&out[((size_t)b * 1024 + n) * 128 + ob] = pk;
        }
    }
#pragma unroll
    for (int off = 32; off > 0; off >>= 1) {
        lsum += __shfl_down(lsum, off);
        lsq  += __shfl_down(lsq, off);
    }
    float* red = (float*)wt8;  // wt dead after K-loop
    if (lane == 0) { red[wave] = lsum; red[4 + wave] = lsq; }
    __syncthreads();
    if (tid == 0) {
        atomicAdd(&sums[2 * b + 0], red[0] + red[1] + red[2] + red[3]);
        atomicAdd(&sums[2 * b + 1], red[4] + red[5] + red[6] + red[7]);
    }
}

// pooled max -> normalize -> fc1+lrelu -> fc2
__global__ __launch_bounds__(64) void fc_head(
    const float* __restrict__ pmax, const float* __restrict__ sums3, float count,
    const float* __restrict__ w_fc1, const float* __restrict__ b_fc1,
    const float* __restrict__ w_fc2, const float* __restrict__ b_fc2,
    float* __restrict__ y)
{
    const int b = blockIdx.x, t = threadIdx.x;
    __shared__ float pooled[64];
    __shared__ float hid[32];
    float2 s = stats_from(sums3, b, count);
    pooled[t] = (pmax[(size_t)b * 64 + t] - s.x) * s.y;
    __syncthreads();
    if (t < 32) {
        float h = b_fc1[t];
#pragma unroll
        for (int c = 0; c < 64; c++) h += pooled[c] * w_fc1[t * 64 + c];
        hid[t] = LRELU(h);
    }
    __syncthreads();
    if (t == 0) {
        float v = b_fc2[0];
#pragma unroll
        for (int c = 0; c < 32; c++) v += hid[c] * w_fc2[c];
        y[b] = v;
    }
}

__global__ void sigmoid_diff(const float* __restrict__ y1,
                             const float* __restrict__ y2,
                             float* __restrict__ out)
{
    int b = threadIdx.x;
    if (b < 128) out[b] = 1.0f / (1.0f + expf(-(y1[b] - y2[b])));
}

extern "C" void kernel_launch(void* const* d_in, const int* in_sizes, int n_in,
                              void* d_out, int out_size, void* d_ws, size_t ws_size,
                              hipStream_t stream)
{
    const float* data1 = (const float*)d_in[0];
    const int*   idx1  = (const int*)d_in[1];
    const float* data2 = (const float*)d_in[2];
    const int*   idx2  = (const int*)d_in[3];
    const float* w1 = (const float*)d_in[4];
    const float* b1 = (const float*)d_in[5];
    const float* w2 = (const float*)d_in[6];
    const float* b2 = (const float*)d_in[7];
    const float* w3 = (const float*)d_in[8];
    const float* b3 = (const float*)d_in[9];
    const float* wfc1 = (const float*)d_in[10];
    const float* bfc1 = (const float*)d_in[11];
    const float* wfc2 = (const float*)d_in[12];
    const float* bfc2 = (const float*)d_in[13];

    // a1 is fp8 (1B/elem); xT and a2 stay bf16
    const size_t needM = (size_t)256 * 1024 * (64 * 2 + 256 * 1 + 128 * 2) + 768 * 1024;
    const bool merged = ws_size >= needM;
    const int nB = merged ? 256 : 128;
    const size_t szXT = (size_t)nB * 1024 * 64 * 2;
    const size_t szA1 = (size_t)nB * 1024 * 256;       // fp8
    const size_t szA2 = (size_t)nB * 1024 * 128 * 2;

    char* ws = (char*)d_ws;
    unsigned short* xT = (unsigned short*)ws;
    unsigned char*  a1 = (unsigned char*)(ws + szXT);
    unsigned short* a2 = (unsigned short*)(ws + szXT + szA1);
    char* tail = ws + szXT + szA1 + szA2;
    unsigned short* wq1 = (unsigned short*)tail;                 // 96 KB
    unsigned char*  wq2f8 = (unsigned char*)(tail + 128 * 1024); // 96 KB (fp8)
    unsigned short* wq3 = (unsigned short*)(tail + 384 * 1024);  // 48 KB
    float* sums = (float*)(tail + 448 * 1024);                   // 3*nB*2 f32
    float* pmax = (float*)(tail + 512 * 1024);                   // nB*64 f32
    float* yv   = (float*)(tail + 640 * 1024);                   // 256 f32

    prep_all<<<96, 256, 0, stream>>>(w1, wq1, w2, wq2f8, w3, wq3);

    const int nIter = merged ? 1 : 2;
    for (int t = 0; t < nIter; ++t) {
        const float* dA = (merged || t == 0) ? data1 : data2;
        const float* dB = merged ? data2 : dA;
        const int* iA = (merged || t == 0) ? idx1 : idx2;
        const int* iB = merged ? idx2 : iA;
        float* s1 = sums;
        float* s2 = sums + nB * 2;
        float* s3 = sums + nB * 4;

        // sums/pmax re-init folded into transpose_in block (0,0)
        transpose_in<<<dim3(16, nB), 256, 0, stream>>>(dA, dB, xT, sums,
                                                       (unsigned int*)pmax);

        // conv1: bf16 in, fp8 out (halves the 134MB streaming write)
        conv_mfma<128, false, false, false, true><<<dim3(nB, 2, 8), 256, 0, stream>>>(
            xT, iA, iB, wq1, b1, a1, s1, nullptr, nullptr, 0.0f, 64, 6, 256, 192);

        // R12: normalize+lrelu a1 ONCE (in place), then pure-copy fp8 MFMA conv2
        norm_act_fp8<<<dim3(16, nB), 256, 0, stream>>>(a1, s1, 256.0f * 1024.0f);

        conv2_fp8<<<dim3(nB, 1, 8), 256, 0, stream>>>(
            a1, iA, iB, wq2f8, b2, a2, s2);

        conv_mfma<64, true, true, false, false><<<dim3(nB, 1, 8), 256, 0, stream>>>(
            a2, iA, iB, wq3, b3, nullptr, s3, pmax, s2, 128.0f * 1024.0f, 128, 7, 64, 384);

        fc_head<<<nB, 64, 0, stream>>>(pmax, s3, 64.0f * 1024.0f,
                                       wfc1, bfc1, wfc2, bfc2,
                                       yv + (merged ? 0 : t * 128));
    }
    sigmoid_diff<<<1, 128, 0, stream>>>(yv, yv + 128, (float*)d_out);
}

// Round 4
// 281.625 us; speedup vs baseline: 1.1555x; 1.1296x over previous
//
#include <hip/hip_runtime.h>
#include <math.h>

typedef __attribute__((ext_vector_type(8))) short short8;
typedef __attribute__((ext_vector_type(4))) float f32x4;
typedef __attribute__((ext_vector_type(2))) float f32x2;

#define LRELU(x) ((x) > 0.0f ? (x) : 0.01f * (x))

struct __align__(4) Int3 { int x, y, z; };

__device__ __forceinline__ unsigned short f2bf(float f) {
    unsigned int u = __float_as_uint(f);
    return (unsigned short)((u + 0x7FFFu + ((u >> 16) & 1u)) >> 16);
}
// round-half-up bf16 pair pack: ~5 VALU vs ~10 for RNE; <=0.5 ULP error
__device__ __forceinline__ unsigned int pack_bf16_pair(float lo, float hi) {
    unsigned int ul = __float_as_uint(lo) + 0x8000u;
    unsigned int uh = __float_as_uint(hi) + 0x8000u;
    return (ul >> 16) | (uh & 0xFFFF0000u);
}
__device__ __forceinline__ float2 stats_from(const float* sums, int b, float count) {
    float s = sums[2 * b], q = sums[2 * b + 1];
    float mean = s / count;
    float var = (q - s * s / count) / (count - 1.0f);  // ddof=1
    var = fmaxf(var, 0.0f);
    return make_float2(mean, 1.0f / (sqrtf(var) + 1e-5f));
}
// init pattern 0xFFFFFFFF (-NaN): positives via signed max, negatives via unsigned min
__device__ __forceinline__ void atomicMaxF(float* a, float v) {
    if (v >= 0.0f) atomicMax((int*)a, __float_as_int(v));
    else           atomicMin((unsigned int*)a, __float_as_uint(v));
}
// 4 fp8 e4m3 -> lrelu(x*a+c) -> 4 fp8 e4m3 (in-register, for the norm_act passes)
__device__ __forceinline__ unsigned int fp8x4_nact(unsigned int u, float a, float c) {
    f32x2 lo = __builtin_amdgcn_cvt_pk_f32_fp8(u, false);
    f32x2 hi = __builtin_amdgcn_cvt_pk_f32_fp8(u, true);
    lo = lo * a + c; hi = hi * a + c;
    f32x2 ml = lo * 0.01f, mh = hi * 0.01f;
    lo = __builtin_elementwise_max(lo, ml);
    hi = __builtin_elementwise_max(hi, mh);
    int r = __builtin_amdgcn_cvt_pk_fp8_f32(lo.x, lo.y, 0, false);
    r = __builtin_amdgcn_cvt_pk_fp8_f32(hi.x, hi.y, r, true);
    return (unsigned int)r;
}

// MFMA fragment block (bf16): LDS -> frags -> 2 k-stages of 16x16x32 bf16 MFMAs
template <int MT, int WM>
__device__ __forceinline__ void mfma_step(const unsigned short* wt, const unsigned short* gt,
                                          f32x4 (&acc)[MT][4],
                                          int wo, int wn, int quad, int l15, int blkid)
{
#pragma unroll
    for (int st = 0; st < 2; ++st) {
        short8 af[MT], bfv[4];
        const int qb = st * 4 + quad;
#pragma unroll
        for (int i = 0; i < MT; i++) {
            const int orow = wo * WM + i * 16 + l15;
            af[i] = *(const short8*)&wt[orow * 64 + ((qb ^ blkid) << 3)];
        }
#pragma unroll
        for (int t = 0; t < 4; t++) {
            const int nrow = wn * 64 + t * 16 + l15;
            bfv[t] = *(const short8*)&gt[nrow * 64 + ((qb ^ blkid) << 3)];
        }
#pragma unroll
        for (int i = 0; i < MT; i++)
#pragma unroll
            for (int t = 0; t < 4; t++)
                acc[i][t] = __builtin_amdgcn_mfma_f32_16x16x32_bf16(
                    af[i], bfv[t], acc[i][t], 0, 0, 0);
    }
}

// R14: w1 -> bf16 [256][192]; w2 -> fp8 [128][768]; w3 -> fp8 [64][384]
__global__ void prep_all(const float* __restrict__ w1, unsigned short* __restrict__ wq1,
                         const float* __restrict__ w2, unsigned char* __restrict__ wq2,
                         const float* __restrict__ w3, unsigned char* __restrict__ wq3)
{
    const int tid = blockIdx.x * blockDim.x + threadIdx.x;
    const int stride = gridDim.x * blockDim.x;
    for (int i = tid; i < 256 * 192; i += stride) {
        int o = i / 192, kp = i - o * 192;
        int j = kp >> 6, c = kp & 63;
        wq1[i] = f2bf(w1[(o * 64 + c) * 3 + j]);
    }
    for (int i = tid; i < (128 * 768) >> 2; i += stride) {
        const int e0 = i << 2;
        const int o = e0 / 768, kp0 = e0 - o * 768;
        const int j = kp0 >> 8, c0 = kp0 & 255;
        const float* src = &w2[(o * 256 + c0) * 3 + j];
        float f0 = src[0], f1 = src[3], f2 = src[6], f3 = src[9];
        int r = __builtin_amdgcn_cvt_pk_fp8_f32(f0, f1, 0, false);
        r = __builtin_amdgcn_cvt_pk_fp8_f32(f2, f3, r, true);
        *(unsigned int*)&wq2[e0] = (unsigned int)r;
    }
    for (int i = tid; i < (64 * 384) >> 2; i += stride) {
        const int e0 = i << 2;
        const int o = e0 / 384, kp0 = e0 - o * 384;
        const int j = kp0 >> 7, c0 = kp0 & 127;
        const float* src = &w3[(o * 128 + c0) * 3 + j];
        float f0 = src[0], f1 = src[3], f2 = src[6], f3 = src[9];
        int r = __builtin_amdgcn_cvt_pk_fp8_f32(f0, f1, 0, false);
        r = __builtin_amdgcn_cvt_pk_fp8_f32(f2, f3, r, true);
        *(unsigned int*)&wq3[e0] = (unsigned int)r;
    }
}

// data [128][64][1024] f32 -> xT [nB][1024][64] bf16 (tower select on b>=128)
// block (0,0) also re-inits sums/pmax (replaces 2 hipMemsetAsync dispatches)
__global__ __launch_bounds__(256) void transpose_in(const float* __restrict__ inA,
                                                    const float* __restrict__ inB,
                                                    unsigned short* __restrict__ xT,
                                                    float* __restrict__ sums,
                                                    unsigned int* __restrict__ pmax)
{
    const int b = blockIdx.y, n0 = blockIdx.x * 64;
    const float* in = (b >= 128 ? inB : inA) + ((size_t)(b & 127) * 64) * 1024;
    const int tid = threadIdx.x;
    if (blockIdx.x == 0 && blockIdx.y == 0) {
        const int nBv = gridDim.y;
        for (int i = tid; i < 3 * nBv * 2; i += 256) sums[i] = 0.0f;
        for (int i = tid; i < nBv * 64; i += 256) pmax[i] = 0xFFFFFFFFu;
    }
    __shared__ float tile[64][65];
    const int nn = tid & 63, cw = tid >> 6;
#pragma unroll
    for (int i = 0; i < 16; i++) {
        int c = i * 4 + cw;
        tile[c][nn] = in[(size_t)c * 1024 + n0 + nn];
    }
    __syncthreads();
    const int n = tid >> 2, cp = (tid & 3) * 16;
    unsigned int pk[8];
#pragma unroll
    for (int i = 0; i < 8; i++) {
        unsigned short lo = f2bf(tile[cp + 2 * i][n]);
        unsigned short hi = f2bf(tile[cp + 2 * i + 1][n]);
        pk[i] = (unsigned int)lo | ((unsigned int)hi << 16);
    }
    unsigned short* dst = xT + ((size_t)b * 1024 + n0 + n) * 64 + cp;
    uint4 v0 = {pk[0], pk[1], pk[2], pk[3]};
    uint4 v1 = {pk[4], pk[5], pk[6], pk[7]};
    *(uint4*)dst = v0;
    *(uint4*)(dst + 8) = v1;
}

// apply lrelu(norm(.)) ONCE per element (in place). u4PerB = uint4s per batch row.
__global__ __launch_bounds__(256) void norm_act_fp8(unsigned char* __restrict__ a,
                                                    const float* __restrict__ sums,
                                                    float count, int u4PerB)
{
    const int b = blockIdx.y;
    float2 st = stats_from(sums, b, count);
    const float na = st.y, nc = -st.x * st.y;
    uint4* p = (uint4*)a + (size_t)b * u4PerB;
    for (int idx = blockIdx.x * 256 + threadIdx.x; idx < u4PerB; idx += gridDim.x * 256) {
        uint4 v = p[idx];
        v.x = fp8x4_nact(v.x, na, nc);
        v.y = fp8x4_nact(v.y, na, nc);
        v.z = fp8x4_nact(v.z, na, nc);
        v.w = fp8x4_nact(v.w, na, nc);
        p[idx] = v;
    }
}

// R14 theory: convs are ADDRESS-ISSUE bound (~1 lane-request/cy/CU; R13: +50%
// occupancy -> 0 speedup, all pipes <30%). Levers = fewer/fatter requests:
//  - epilogue: pack results to LDS (bank-swizzled), then dense 16B/lane stores
//    (4096 -> 1024 store requests/block); also kills partial-line write amp.
//  - idx triple as one 12B load.
// __launch_bounds__(256,3); named scalars only (local arrays -> scratch).
__global__ __launch_bounds__(256, 3) void conv1_mfma(
    const unsigned short* __restrict__ xT,   // [nB][1024][64] bf16
    const int* __restrict__ idxA,            // [128][3069]
    const int* __restrict__ idxB,
    const unsigned short* __restrict__ wq,   // [256][192] bf16 (k'=j*64+c)
    const float* __restrict__ bias,          // [256] f32
    unsigned char* __restrict__ out,         // [nB][1024][256] fp8 raw
    float* __restrict__ sums)                // [nB][2]
{
    const int b   = blockIdx.x;
    const int o0  = blockIdx.y * 128;
    const int nt0 = blockIdx.z << 7;
    const int tid = threadIdx.x;
    const int lane = tid & 63, wave = tid >> 6;
    const int wo = wave & 1, wn = wave >> 1;
    const int quad = lane >> 4, l15 = lane & 15;
    const int blkid = lane & 7;

    __shared__ __align__(16) unsigned short wt[128 * 64];
    __shared__ __align__(16) unsigned short gt[128 * 64];

    f32x4 acc[4][4];
#pragma unroll
    for (int i = 0; i < 4; i++)
#pragma unroll
        for (int t = 0; t < 4; t++) acc[i][t] = (f32x4){0.f, 0.f, 0.f, 0.f};

    const unsigned short* xTb = xT + (((size_t)b) << 10) * 64;
    const int* idxb = (b >= 128 ? idxB : idxA) + (size_t)(b & 127) * 3069;

    const int gr = tid >> 1, gh = tid & 1;       // gt row (n), 32-channel half
    int s0, s1, s2;
    {
        int n = nt0 + gr;
        int t0 = (n == 0) ? 0 : (n - 1);         // n==0 row is garbage, zeroed later
        const Int3 sv = *(const Int3*)&idxb[3 * t0];
        s0 = sv.x; s1 = sv.y; s2 = sv.z;
    }
    const int wr = tid >> 1, wseg = tid & 1;     // wt row (o), 64B-half
    const unsigned short* wrow = wq + (size_t)(o0 + wr) * 192 + wseg * 32;
    const int gswz = gr & 7, wswz = wr & 7;

    uint4 g0A, g1A, g2A, g3A;
    uint4 g0B, g1B, g2B, g3B;

#define LOADC(S, KC) {                                                           \
        const int src_ = ((KC) == 0) ? s0 : (((KC) == 1) ? s1 : s2);             \
        const uint4* gp_ = (const uint4*)(xTb + (size_t)src_ * 64 + gh * 32);    \
        g0##S = gp_[0]; g1##S = gp_[1]; g2##S = gp_[2]; g3##S = gp_[3];          \
    }

// weights 1-deep here (L2-hot; latency hidden under the gt LDS writes)
#define STAGE(S, KC) {                                                           \
        const uint4* wp_ = (const uint4*)(wrow + ((KC) << 6));                   \
        uint4 wv0 = wp_[0], wv1 = wp_[1], wv2 = wp_[2], wv3 = wp_[3];            \
        *(uint4*)&gt[gr * 64 + (((gh << 2) | 0) ^ gswz) * 8] = g0##S;            \
        *(uint4*)&gt[gr * 64 + (((gh << 2) | 1) ^ gswz) * 8] = g1##S;            \
        *(uint4*)&gt[gr * 64 + (((gh << 2) | 2) ^ gswz) * 8] = g2##S;            \
        *(uint4*)&gt[gr * 64 + (((gh << 2) | 3) ^ gswz) * 8] = g3##S;            \
        *(uint4*)&wt[wr * 64 + ((wseg * 4 + 0) ^ wswz) * 8] = wv0;               \
        *(uint4*)&wt[wr * 64 + ((wseg * 4 + 1) ^ wswz) * 8] = wv1;               \
        *(uint4*)&wt[wr * 64 + ((wseg * 4 + 2) ^ wswz) * 8] = wv2;               \
        *(uint4*)&wt[wr * 64 + ((wseg * 4 + 3) ^ wswz) * 8] = wv3;               \
    }

    // 3 chunks, 2-deep register pipeline, odd tail
    LOADC(A, 0);
    LOADC(B, 1);
    int kc = 0;
    for (; kc + 2 <= 3; kc += 2) {
        if (kc) __syncthreads();
        STAGE(A, kc);
        if (kc + 2 < 3) LOADC(A, kc + 2);
        __syncthreads();
        mfma_step<4, 64>(wt, gt, acc, wo, wn, quad, l15, blkid);
        __syncthreads();
        STAGE(B, kc + 1);
        __syncthreads();
        mfma_step<4, 64>(wt, gt, acc, wo, wn, quad, l15, blkid);
    }
    {   // tail chunk 2 (set A)
        __syncthreads();
        STAGE(A, 2);
        __syncthreads();
        mfma_step<4, 64>(wt, gt, acc, wo, wn, quad, l15, blkid);
    }
#undef LOADC
#undef STAGE

    __syncthreads();                 // all LDS readers done (also fixes red race)
    unsigned char* eb = (unsigned char*)gt;   // [128 n][128 o] fp8, bank-swizzled
    float lsum = 0.f, lsq = 0.f;
#pragma unroll
    for (int i = 0; i < 4; i++) {
        const int obl = wo * 64 + i * 16 + quad * 4;
        const float4 bv = *(const float4*)(bias + o0 + obl);
#pragma unroll
        for (int t = 0; t < 4; t++) {
            const int nl = wn * 64 + t * 16 + l15;
            float v0 = acc[i][t][0] + bv.x;
            float v1 = acc[i][t][1] + bv.y;
            float v2 = acc[i][t][2] + bv.z;
            float v3 = acc[i][t][3] + bv.w;
            if (nt0 + nl == 0) { v0 = v1 = v2 = v3 = 0.f; }
            lsum += v0 + v1 + v2 + v3;
            lsq  += v0 * v0 + v1 * v1 + v2 * v2 + v3 * v3;
            int r = __builtin_amdgcn_cvt_pk_fp8_f32(v0, v1, 0, false);
            r = __builtin_amdgcn_cvt_pk_fp8_f32(v2, v3, r, true);
            *(unsigned int*)&eb[nl * 128 + (obl ^ ((nl & 7) << 4))] = (unsigned int)r;
        }
    }
#pragma unroll
    for (int off = 32; off > 0; off >>= 1) {
        lsum += __shfl_down(lsum, off);
        lsq  += __shfl_down(lsq, off);
    }
    float* red = (float*)wt;
    if (lane == 0) { red[wave] = lsum; red[4 + wave] = lsq; }
    __syncthreads();
    // dense store: 128 rows x 128B tile -> 16B/lane
#pragma unroll
    for (int c = 0; c < 4; ++c) {
        const int ch = c * 256 + tid;
        const int row = ch >> 3, off = (ch & 7) << 4;
        uint4 v = *(const uint4*)&eb[row * 128 + (off ^ ((row & 7) << 4))];
        *(uint4*)&out[((size_t)b * 1024 + nt0 + row) * 256 + o0 + off] = v;
    }
    if (tid == 0) {
        atomicAdd(&sums[2 * b + 0], red[0] + red[1] + red[2] + red[3]);
        atomicAdd(&sums[2 * b + 1], red[4] + red[5] + red[6] + red[7]);
    }
}

// conv2: pure-copy-stage fp8 x fp8 MFMA (inputs pre-normalized, weights e4m3).
// R14: out is fp8 (a2), epilogue via LDS roundtrip -> 16B/lane dense stores.
__global__ __launch_bounds__(256, 3) void conv2_fp8(
    const unsigned char* __restrict__ a1,    // [nB][1024][256] fp8, normalized
    const int* __restrict__ idxA,
    const int* __restrict__ idxB,
    const unsigned char* __restrict__ wq8,   // [128][768] fp8 e4m3
    const float* __restrict__ bias,          // [128] f32
    unsigned char* __restrict__ out,         // [nB][1024][128] fp8 raw
    float* __restrict__ sums)                // [nB][2]
{
    const int b   = blockIdx.x;
    const int nt0 = blockIdx.z << 7;
    const int tid = threadIdx.x;
    const int lane = tid & 63, wave = tid >> 6;
    const int wo = wave & 1, wn = wave >> 1;
    const int quad = lane >> 4, l15 = lane & 15;
    const int blkid = lane & 7;

    __shared__ __align__(16) unsigned char wt8[128 * 128];
    __shared__ __align__(16) unsigned char gt8[128 * 128];

    f32x4 acc[4][4];
#pragma unroll
    for (int i = 0; i < 4; i++)
#pragma unroll
        for (int t = 0; t < 4; t++) acc[i][t] = (f32x4){0.f, 0.f, 0.f, 0.f};

    const unsigned char* xb = a1 + (((size_t)b) << 10) * 256;
    const int* idxb = (b >= 128 ? idxB : idxA) + (size_t)(b & 127) * 3069;

    const int gr = tid >> 1, gh = tid & 1;   // row, 64B-half (same for gt and wt)
    int si0, si1, si2;
    {
        int n = nt0 + gr;
        int t0 = (n == 0) ? 0 : (n - 1);
        const Int3 sv = *(const Int3*)&idxb[3 * t0];
        si0 = sv.x; si1 = sv.y; si2 = sv.z;
    }
    const unsigned char* wrow = wq8 + (size_t)gr * 768 + gh * 64;
    const int swz = gr & 7;

    uint4 g0A, g1A, g2A, g3A;
    uint4 g0B, g1B, g2B, g3B;

#define LOADC2(S, KC) {                                                          \
        const int j_  = (KC) >> 1;                                               \
        const int c0_ = ((KC) & 1) << 7;                                         \
        const int src_ = (j_ == 0) ? si0 : ((j_ == 1) ? si1 : si2);              \
        const uint4* gp_ = (const uint4*)(xb + (size_t)src_ * 256 + c0_ + gh * 64); \
        g0##S = gp_[0]; g1##S = gp_[1]; g2##S = gp_[2]; g3##S = gp_[3];          \
    }

#define STAGE2(S, KC) {                                                          \
        const uint4* wp_ = (const uint4*)(wrow + (KC) * 128);                    \
        uint4 wv0 = wp_[0], wv1 = wp_[1], wv2 = wp_[2], wv3 = wp_[3];            \
        *(uint4*)&gt8[gr * 128 + (((gh << 2) | 0) ^ swz) * 16] = g0##S;          \
        *(uint4*)&gt8[gr * 128 + (((gh << 2) | 1) ^ swz) * 16] = g1##S;          \
        *(uint4*)&gt8[gr * 128 + (((gh << 2) | 2) ^ swz) * 16] = g2##S;          \
        *(uint4*)&gt8[gr * 128 + (((gh << 2) | 3) ^ swz) * 16] = g3##S;          \
        *(uint4*)&wt8[gr * 128 + (((gh << 2) | 0) ^ swz) * 16] = wv0;            \
        *(uint4*)&wt8[gr * 128 + (((gh << 2) | 1) ^ swz) * 16] = wv1;            \
        *(uint4*)&wt8[gr * 128 + (((gh << 2) | 2) ^ swz) * 16] = wv2;            \
        *(uint4*)&wt8[gr * 128 + (((gh << 2) | 3) ^ swz) * 16] = wv3;            \
    }

#define MFMA_STEP2 {                                                             \
        _Pragma("unroll")                                                        \
        for (int st = 0; st < 4; ++st) {                                         \
            long af0, af1, af2, af3, bf0, bf1, bf2, bf3;                         \
            const int qb = st * 4 + quad;                                        \
            const int cg = qb >> 1, ch = (qb & 1) << 3;                          \
            {                                                                    \
                const int r0 = wo * 64 + 0 * 16 + l15;                           \
                af0 = *(const long*)&wt8[r0 * 128 + ((cg ^ blkid) << 4) + ch];   \
                const int r1 = wo * 64 + 1 * 16 + l15;                           \
                af1 = *(const long*)&wt8[r1 * 128 + ((cg ^ blkid) << 4) + ch];   \
                const int r2 = wo * 64 + 2 * 16 + l15;                           \
                af2 = *(const long*)&wt8[r2 * 128 + ((cg ^ blkid) << 4) + ch];   \
                const int r3 = wo * 64 + 3 * 16 + l15;                           \
                af3 = *(const long*)&wt8[r3 * 128 + ((cg ^ blkid) << 4) + ch];   \
                const int n0 = wn * 64 + 0 * 16 + l15;                           \
                bf0 = *(const long*)&gt8[n0 * 128 + ((cg ^ blkid) << 4) + ch];   \
                const int n1 = wn * 64 + 1 * 16 + l15;                           \
                bf1 = *(const long*)&gt8[n1 * 128 + ((cg ^ blkid) << 4) + ch];   \
                const int n2 = wn * 64 + 2 * 16 + l15;                           \
                bf2 = *(const long*)&gt8[n2 * 128 + ((cg ^ blkid) << 4) + ch];   \
                const int n3 = wn * 64 + 3 * 16 + l15;                           \
                bf3 = *(const long*)&gt8[n3 * 128 + ((cg ^ blkid) << 4) + ch];   \
            }                                                                    \
            acc[0][0] = __builtin_amdgcn_mfma_f32_16x16x32_fp8_fp8(af0, bf0, acc[0][0], 0, 0, 0); \
            acc[0][1] = __builtin_amdgcn_mfma_f32_16x16x32_fp8_fp8(af0, bf1, acc[0][1], 0, 0, 0); \
            acc[0][2] = __builtin_amdgcn_mfma_f32_16x16x32_fp8_fp8(af0, bf2, acc[0][2], 0, 0, 0); \
            acc[0][3] = __builtin_amdgcn_mfma_f32_16x16x32_fp8_fp8(af0, bf3, acc[0][3], 0, 0, 0); \
            acc[1][0] = __builtin_amdgcn_mfma_f32_16x16x32_fp8_fp8(af1, bf0, acc[1][0], 0, 0, 0); \
            acc[1][1] = __builtin_amdgcn_mfma_f32_16x16x32_fp8_fp8(af1, bf1, acc[1][1], 0, 0, 0); \
            acc[1][2] = __builtin_amdgcn_mfma_f32_16x16x32_fp8_fp8(af1, bf2, acc[1][2], 0, 0, 0); \
            acc[1][3] = __builtin_amdgcn_mfma_f32_16x16x32_fp8_fp8(af1, bf3, acc[1][3], 0, 0, 0); \
            acc[2][0] = __builtin_amdgcn_mfma_f32_16x16x32_fp8_fp8(af2, bf0, acc[2][0], 0, 0, 0); \
            acc[2][1] = __builtin_amdgcn_mfma_f32_16x16x32_fp8_fp8(af2, bf1, acc[2][1], 0, 0, 0); \
            acc[2][2] = __builtin_amdgcn_mfma_f32_16x16x32_fp8_fp8(af2, bf2, acc[2][2], 0, 0, 0); \
            acc[2][3] = __builtin_amdgcn_mfma_f32_16x16x32_fp8_fp8(af2, bf3, acc[2][3], 0, 0, 0); \
            acc[3][0] = __builtin_amdgcn_mfma_f32_16x16x32_fp8_fp8(af3, bf0, acc[3][0], 0, 0, 0); \
            acc[3][1] = __builtin_amdgcn_mfma_f32_16x16x32_fp8_fp8(af3, bf1, acc[3][1], 0, 0, 0); \
            acc[3][2] = __builtin_amdgcn_mfma_f32_16x16x32_fp8_fp8(af3, bf2, acc[3][2], 0, 0, 0); \
            acc[3][3] = __builtin_amdgcn_mfma_f32_16x16x32_fp8_fp8(af3, bf3, acc[3][3], 0, 0, 0); \
        }                                                                        \
    }

    LOADC2(A, 0);
    LOADC2(B, 1);
    int kc = 0;
    for (; kc + 2 <= 6; kc += 2) {
        if (kc) __syncthreads();
        STAGE2(A, kc);
        if (kc + 2 < 6) LOADC2(A, kc + 2);
        __syncthreads();
        MFMA_STEP2;
        __syncthreads();
        STAGE2(B, kc + 1);
        if (kc + 3 < 6) LOADC2(B, kc + 3);
        __syncthreads();
        MFMA_STEP2;
    }
#undef LOADC2
#undef STAGE2
#undef MFMA_STEP2

    __syncthreads();                 // all LDS readers done
    unsigned char* eb = gt8;         // [128 n][128 o] fp8, bank-swizzled
    float lsum = 0.f, lsq = 0.f;
#pragma unroll
    for (int i = 0; i < 4; i++) {
        const int obl = wo * 64 + i * 16 + quad * 4;
        const float4 bv = *(const float4*)(bias + obl);
#pragma unroll
        for (int t = 0; t < 4; t++) {
            const int nl = wn * 64 + t * 16 + l15;
            float v0 = acc[i][t][0] + bv.x;
            float v1 = acc[i][t][1] + bv.y;
            float v2 = acc[i][t][2] + bv.z;
            float v3 = acc[i][t][3] + bv.w;
            if (nt0 + nl == 0) { v0 = v1 = v2 = v3 = 0.f; }
            lsum += v0 + v1 + v2 + v3;
            lsq  += v0 * v0 + v1 * v1 + v2 * v2 + v3 * v3;
            int r = __builtin_amdgcn_cvt_pk_fp8_f32(v0, v1, 0, false);
            r = __builtin_amdgcn_cvt_pk_fp8_f32(v2, v3, r, true);
            *(unsigned int*)&eb[nl * 128 + (obl ^ ((nl & 7) << 4))] = (unsigned int)r;
        }
    }
#pragma unroll
    for (int off = 32; off > 0; off >>= 1) {
        lsum += __shfl_down(lsum, off);
        lsq  += __shfl_down(lsq, off);
    }
    float* red = (float*)wt8;
    if (lane == 0) { red[wave] = lsum; red[4 + wave] = lsq; }
    __syncthreads();
#pragma unroll
    for (int c = 0; c < 4; ++c) {
        const int ch = c * 256 + tid;
        const int row = ch >> 3, off = (ch & 7) << 4;
        uint4 v = *(const uint4*)&eb[row * 128 + (off ^ ((row & 7) << 4))];
        *(uint4*)&out[((size_t)b * 1024 + nt0 + row) * 128 + off] = v;
    }
    if (tid == 0) {
        atomicAdd(&sums[2 * b + 0], red[0] + red[1] + red[2] + red[3]);
        atomicAdd(&sums[2 * b + 1], red[4] + red[5] + red[6] + red[7]);
    }
}

// R14: conv3 as pure-copy fp8 x fp8 MFMA (a2 pre-normalized by norm_act_fp8).
// O=64, Cin=128, K=384 -> 3 chunks of 128 k. POOL epilogue (no stores).
__global__ __launch_bounds__(256, 3) void conv3_fp8(
    const unsigned char* __restrict__ a2,    // [nB][1024][128] fp8, normalized
    const int* __restrict__ idxA,
    const int* __restrict__ idxB,
    const unsigned char* __restrict__ wq8,   // [64][384] fp8 e4m3
    const float* __restrict__ bias,          // [64] f32
    float* __restrict__ sums,                // [nB][2]
    float* __restrict__ pmax)                // [nB][64]
{
    const int b   = blockIdx.x;
    const int nt0 = blockIdx.z << 7;
    const int tid = threadIdx.x;
    const int lane = tid & 63, wave = tid >> 6;
    const int wo = wave & 1, wn = wave >> 1;
    const int quad = lane >> 4, l15 = lane & 15;
    const int blkid = lane & 7;

    __shared__ __align__(16) unsigned char wt8[64 * 128];
    __shared__ __align__(16) unsigned char gt8[128 * 128];

    f32x4 acc[2][4];
#pragma unroll
    for (int i = 0; i < 2; i++)
#pragma unroll
        for (int t = 0; t < 4; t++) acc[i][t] = (f32x4){0.f, 0.f, 0.f, 0.f};

    const unsigned char* xb = a2 + (((size_t)b) << 10) * 128;
    const int* idxb = (b >= 128 ? idxB : idxA) + (size_t)(b & 127) * 3069;

    const int gr = tid >> 1, gh = tid & 1;       // gt row, 64B-half
    int si0, si1, si2;
    {
        int n = nt0 + gr;
        int t0 = (n == 0) ? 0 : (n - 1);
        const Int3 sv = *(const Int3*)&idxb[3 * t0];
        si0 = sv.x; si1 = sv.y; si2 = sv.z;
    }
    const int wr = tid >> 2, wseg = tid & 3;     // wt row (o), 32B segment
    const unsigned char* wrow = wq8 + (size_t)wr * 384 + wseg * 32;
    const int gswz = gr & 7, wswz = wr & 7;

    uint4 g0A, g1A, g2A, g3A;
    uint4 g0B, g1B, g2B, g3B;

#define LOADC3(S, KC) {                                                          \
        const int src_ = ((KC) == 0) ? si0 : (((KC) == 1) ? si1 : si2);          \
        const uint4* gp_ = (const uint4*)(xb + (size_t)src_ * 128 + gh * 64);    \
        g0##S = gp_[0]; g1##S = gp_[1]; g2##S = gp_[2]; g3##S = gp_[3];          \
    }

#define STAGE3(S, KC) {                                                          \
        const uint4* wp_ = (const uint4*)(wrow + (KC) * 128);                    \
        uint4 wv0 = wp_[0], wv1 = wp_[1];                                        \
        *(uint4*)&gt8[gr * 128 + (((gh << 2) | 0) ^ gswz) * 16] = g0##S;         \
        *(uint4*)&gt8[gr * 128 + (((gh << 2) | 1) ^ gswz) * 16] = g1##S;         \
        *(uint4*)&gt8[gr * 128 + (((gh << 2) | 2) ^ gswz) * 16] = g2##S;         \
        *(uint4*)&gt8[gr * 128 + (((gh << 2) | 3) ^ gswz) * 16] = g3##S;         \
        *(uint4*)&wt8[wr * 128 + (((wseg << 1) | 0) ^ wswz) * 16] = wv0;         \
        *(uint4*)&wt8[wr * 128 + (((wseg << 1) | 1) ^ wswz) * 16] = wv1;         \
    }

#define MFMA_STEP3 {                                                             \
        _Pragma("unroll")                                                        \
        for (int st = 0; st < 4; ++st) {                                         \
            long af0, af1, bf0, bf1, bf2, bf3;                                   \
            const int qb = st * 4 + quad;                                        \
            const int cg = qb >> 1, ch = (qb & 1) << 3;                          \
            {                                                                    \
                const int r0 = wo * 32 + 0 * 16 + l15;                           \
                af0 = *(const long*)&wt8[r0 * 128 + ((cg ^ blkid) << 4) + ch];   \
                const int r1 = wo * 32 + 1 * 16 + l15;                           \
                af1 = *(const long*)&wt8[r1 * 128 + ((cg ^ blkid) << 4) + ch];   \
                const int n0 = wn * 64 + 0 * 16 + l15;                           \
                bf0 = *(const long*)&gt8[n0 * 128 + ((cg ^ blkid) << 4) + ch];   \
                const int n1 = wn * 64 + 1 * 16 + l15;                           \
                bf1 = *(const long*)&gt8[n1 * 128 + ((cg ^ blkid) << 4) + ch];   \
                const int n2 = wn * 64 + 2 * 16 + l15;                           \
                bf2 = *(const long*)&gt8[n2 * 128 + ((cg ^ blkid) << 4) + ch];   \
                const int n3 = wn * 64 + 3 * 16 + l15;                           \
                bf3 = *(const long*)&gt8[n3 * 128 + ((cg ^ blkid) << 4) + ch];   \
            }                                                                    \
            acc[0][0] = __builtin_amdgcn_mfma_f32_16x16x32_fp8_fp8(af0, bf0, acc[0][0], 0, 0, 0); \
            acc[0][1] = __builtin_amdgcn_mfma_f32_16x16x32_fp8_fp8(af0, bf1, acc[0][1], 0, 0, 0); \
            acc[0][2] = __builtin_amdgcn_mfma_f32_16x16x32_fp8_fp8(af0, bf2, acc[0][2], 0, 0, 0); \
            acc[0][3] = __builtin_amdgcn_mfma_f32_16x16x32_fp8_fp8(af0, bf3, acc[0][3], 0, 0, 0); \
            acc[1][0] = __builtin_amdgcn_mfma_f32_16x16x32_fp8_fp8(af1, bf0, acc[1][0], 0, 0, 0); \
            acc[1][1] = __builtin_amdgcn_mfma_f32_16x16x32_fp8_fp8(af1, bf1, acc[1][1], 0, 0, 0); \
            acc[1][2] = __builtin_amdgcn_mfma_f32_16x16x32_fp8_fp8(af1, bf2, acc[1][2], 0, 0, 0); \
            acc[1][3] = __builtin_amdgcn_mfma_f32_16x16x32_fp8_fp8(af1, bf3, acc[1][3], 0, 0, 0); \
        }                                                                        \
    }

    LOADC3(A, 0);
    LOADC3(B, 1);
    int kc = 0;
    for (; kc + 2 <= 3; kc += 2) {
        if (kc) __syncthreads();
        STAGE3(A, kc);
        if (kc + 2 < 3) LOADC3(A, kc + 2);
        __syncthreads();
        MFMA_STEP3;
        __syncthreads();
        STAGE3(B, kc + 1);
        __syncthreads();
        MFMA_STEP3;
    }
    {   // tail chunk 2 (set A)
        __syncthreads();
        STAGE3(A, 2);
        __syncthreads();
        MFMA_STEP3;
    }
#undef LOADC3
#undef STAGE3
#undef MFMA_STEP3

    __syncthreads();                 // all LDS readers done before red overlay
    float lsum = 0.f, lsq = 0.f;
#pragma unroll
    for (int i = 0; i < 2; i++) {
        const int ob = wo * 32 + i * 16 + quad * 4;
        const float4 bv = *(const float4*)(bias + ob);
        float mx0 = -1e30f, mx1 = -1e30f, mx2 = -1e30f, mx3 = -1e30f;
#pragma unroll
        for (int t = 0; t < 4; t++) {
            const int n = nt0 + wn * 64 + t * 16 + l15;
            float v0 = acc[i][t][0] + bv.x;
            float v1 = acc[i][t][1] + bv.y;
            float v2 = acc[i][t][2] + bv.z;
            float v3 = acc[i][t][3] + bv.w;
            if (n == 0) { v0 = v1 = v2 = v3 = 0.f; }
            lsum += v0 + v1 + v2 + v3;
            lsq  += v0 * v0 + v1 * v1 + v2 * v2 + v3 * v3;
            mx0 = fmaxf(mx0, v0); mx1 = fmaxf(mx1, v1);
            mx2 = fmaxf(mx2, v2); mx3 = fmaxf(mx3, v3);
        }
#pragma unroll
        for (int off = 1; off < 16; off <<= 1) {
            mx0 = fmaxf(mx0, __shfl_xor(mx0, off));
            mx1 = fmaxf(mx1, __shfl_xor(mx1, off));
            mx2 = fmaxf(mx2, __shfl_xor(mx2, off));
            mx3 = fmaxf(mx3, __shfl_xor(mx3, off));
        }
        if (l15 == 0) {
            atomicMaxF(&pmax[(size_t)b * 64 + ob + 0], mx0);
            atomicMaxF(&pmax[(size_t)b * 64 + ob + 1], mx1);
            atomicMaxF(&pmax[(size_t)b * 64 + ob + 2], mx2);
            atomicMaxF(&pmax[(size_t)b * 64 + ob + 3], mx3);
        }
    }
#pragma unroll
    for (int off = 32; off > 0; off >>= 1) {
        lsum += __shfl_down(lsum, off);
        lsq  += __shfl_down(lsq, off);
    }
    float* red = (float*)wt8;
    if (lane == 0) { red[wave] = lsum; red[4 + wave] = lsq; }
    __syncthreads();
    if (tid == 0) {
        atomicAdd(&sums[2 * b + 0], red[0] + red[1] + red[2] + red[3]);
        atomicAdd(&sums[2 * b + 1], red[4] + red[5] + red[6] + red[7]);
    }
}

// pooled max -> normalize -> fc1+lrelu -> fc2
__global__ __launch_bounds__(64) void fc_head(
    const float* __restrict__ pmax, const float* __restrict__ sums3, float count,
    const float* __restrict__ w_fc1, const float* __restrict__ b_fc1,
    const float* __restrict__ w_fc2, const float* __restrict__ b_fc2,
    float* __restrict__ y)
{
    const int b = blockIdx.x, t = threadIdx.x;
    __shared__ float pooled[64];
    __shared__ float hid[32];
    float2 s = stats_from(sums3, b, count);
    pooled[t] = (pmax[(size_t)b * 64 + t] - s.x) * s.y;
    __syncthreads();
    if (t < 32) {
        float h = b_fc1[t];
#pragma unroll
        for (int c = 0; c < 64; c++) h += pooled[c] * w_fc1[t * 64 + c];
        hid[t] = LRELU(h);
    }
    __syncthreads();
    if (t == 0) {
        float v = b_fc2[0];
#pragma unroll
        for (int c = 0; c < 32; c++) v += hid[c] * w_fc2[c];
        y[b] = v;
    }
}

__global__ void sigmoid_diff(const float* __restrict__ y1,
                             const float* __restrict__ y2,
                             float* __restrict__ out)
{
    int b = threadIdx.x;
    if (b < 128) out[b] = 1.0f / (1.0f + expf(-(y1[b] - y2[b])));
}

extern "C" void kernel_launch(void* const* d_in, const int* in_sizes, int n_in,
                              void* d_out, int out_size, void* d_ws, size_t ws_size,
                              hipStream_t stream)
{
    const float* data1 = (const float*)d_in[0];
    const int*   idx1  = (const int*)d_in[1];
    const float* data2 = (const float*)d_in[2];
    const int*   idx2  = (const int*)d_in[3];
    const float* w1 = (const float*)d_in[4];
    const float* b1 = (const float*)d_in[5];
    const float* w2 = (const float*)d_in[6];
    const float* b2 = (const float*)d_in[7];
    const float* w3 = (const float*)d_in[8];
    const float* b3 = (const float*)d_in[9];
    const float* wfc1 = (const float*)d_in[10];
    const float* bfc1 = (const float*)d_in[11];
    const float* wfc2 = (const float*)d_in[12];
    const float* bfc2 = (const float*)d_in[13];

    // a1 and a2 are fp8 (1B/elem); xT stays bf16
    const size_t needM = (size_t)256 * 1024 * (64 * 2 + 256 * 1 + 128 * 1) + 768 * 1024;
    const bool merged = ws_size >= needM;
    const int nB = merged ? 256 : 128;
    const size_t szXT = (size_t)nB * 1024 * 64 * 2;
    const size_t szA1 = (size_t)nB * 1024 * 256;       // fp8
    const size_t szA2 = (size_t)nB * 1024 * 128;       // fp8

    char* ws = (char*)d_ws;
    unsigned short* xT = (unsigned short*)ws;
    unsigned char*  a1 = (unsigned char*)(ws + szXT);
    unsigned char*  a2 = (unsigned char*)(ws + szXT + szA1);
    char* tail = ws + szXT + szA1 + szA2;
    unsigned short* wq1   = (unsigned short*)tail;               // 96 KB
    unsigned char*  wq2f8 = (unsigned char*)(tail + 128 * 1024); // 96 KB (fp8)
    unsigned char*  wq3f8 = (unsigned char*)(tail + 384 * 1024); // 24 KB (fp8)
    float* sums = (float*)(tail + 448 * 1024);                   // 3*nB*2 f32
    float* pmax = (float*)(tail + 512 * 1024);                   // nB*64 f32
    float* yv   = (float*)(tail + 640 * 1024);                   // 256 f32

    prep_all<<<96, 256, 0, stream>>>(w1, wq1, w2, wq2f8, w3, wq3f8);

    const int nIter = merged ? 1 : 2;
    for (int t = 0; t < nIter; ++t) {
        const float* dA = (merged || t == 0) ? data1 : data2;
        const float* dB = merged ? data2 : dA;
        const int* iA = (merged || t == 0) ? idx1 : idx2;
        const int* iB = merged ? idx2 : iA;
        float* s1 = sums;
        float* s2 = sums + nB * 2;
        float* s3 = sums + nB * 4;

        // sums/pmax re-init folded into transpose_in block (0,0)
        transpose_in<<<dim3(16, nB), 256, 0, stream>>>(dA, dB, xT, sums,
                                                       (unsigned int*)pmax);

        conv1_mfma<<<dim3(nB, 2, 8), 256, 0, stream>>>(
            xT, iA, iB, wq1, b1, a1, s1);

        norm_act_fp8<<<dim3(16, nB), 256, 0, stream>>>(a1, s1, 256.0f * 1024.0f, 16384);

        conv2_fp8<<<dim3(nB, 1, 8), 256, 0, stream>>>(
            a1, iA, iB, wq2f8, b2, a2, s2);

        norm_act_fp8<<<dim3(8, nB), 256, 0, stream>>>(a2, s2, 128.0f * 1024.0f, 8192);

        conv3_fp8<<<dim3(nB, 1, 8), 256, 0, stream>>>(
            a2, iA, iB, wq3f8, b3, s3, pmax);

        fc_head<<<nB, 64, 0, stream>>>(pmax, s3, 64.0f * 1024.0f,
                                       wfc1, bfc1, wfc2, bfc2,
                                       yv + (merged ? 0 : t * 128));
    }
    sigmoid_diff<<<1, 128, 0, stream>>>(yv, yv + 128, (float*)d_out);
}

// Round 5
// 269.467 us; speedup vs baseline: 1.2077x; 1.0451x over previous
//
#include <hip/hip_runtime.h>
#include <math.h>

typedef __attribute__((ext_vector_type(8))) short short8;
typedef __attribute__((ext_vector_type(4))) float f32x4;
typedef __attribute__((ext_vector_type(2))) float f32x2;

#define LRELU(x) ((x) > 0.0f ? (x) : 0.01f * (x))

struct __align__(4) Int3 { int x, y, z; };

__device__ __forceinline__ unsigned short f2bf(float f) {
    unsigned int u = __float_as_uint(f);
    return (unsigned short)((u + 0x7FFFu + ((u >> 16) & 1u)) >> 16);
}
// round-half-up bf16 pair pack: ~5 VALU vs ~10 for RNE; <=0.5 ULP error
__device__ __forceinline__ unsigned int pack_bf16_pair(float lo, float hi) {
    unsigned int ul = __float_as_uint(lo) + 0x8000u;
    unsigned int uh = __float_as_uint(hi) + 0x8000u;
    return (ul >> 16) | (uh & 0xFFFF0000u);
}
__device__ __forceinline__ float2 stats_from(const float* sums, int b, float count) {
    float s = sums[2 * b], q = sums[2 * b + 1];
    float mean = s / count;
    float var = (q - s * s / count) / (count - 1.0f);  // ddof=1
    var = fmaxf(var, 0.0f);
    return make_float2(mean, 1.0f / (sqrtf(var) + 1e-5f));
}
// init pattern 0xFFFFFFFF (-NaN): positives via signed max, negatives via unsigned min
__device__ __forceinline__ void atomicMaxF(float* a, float v) {
    if (v >= 0.0f) atomicMax((int*)a, __float_as_int(v));
    else           atomicMin((unsigned int*)a, __float_as_uint(v));
}
// 4 fp8 e4m3 -> lrelu(x*a+c) -> 4 fp8 e4m3 (in-register, for the norm_act passes)
__device__ __forceinline__ unsigned int fp8x4_nact(unsigned int u, float a, float c) {
    f32x2 lo = __builtin_amdgcn_cvt_pk_f32_fp8(u, false);
    f32x2 hi = __builtin_amdgcn_cvt_pk_f32_fp8(u, true);
    lo = lo * a + c; hi = hi * a + c;
    f32x2 ml = lo * 0.01f, mh = hi * 0.01f;
    lo = __builtin_elementwise_max(lo, ml);
    hi = __builtin_elementwise_max(hi, mh);
    int r = __builtin_amdgcn_cvt_pk_fp8_f32(lo.x, lo.y, 0, false);
    r = __builtin_amdgcn_cvt_pk_fp8_f32(hi.x, hi.y, r, true);
    return (unsigned int)r;
}
// R15 k-byte permutation within each 128-byte chunk: puts the (st,st+1) fragment
// pair for quad q at one contiguous 16B column (p*4+q) -> fp8 frags readable as
// ds_read_b128, same 0-conflict geometry as the bf16 path. perm applied at
// PRODUCERS (conv1/conv2 epilogue channel remap, prep weights); norm_act is
// elementwise and untouched; MFMA semantics bit-exact (same k per MFMA).
__device__ __forceinline__ int perm128(int o) {
    return ((o >> 6) << 6) | (((o >> 3) & 3) << 4) | (((o >> 5) & 1) << 3) | (o & 7);
}

// MFMA fragment block (bf16): LDS -> frags -> 2 k-stages of 16x16x32 bf16 MFMAs
template <int MT, int WM>
__device__ __forceinline__ void mfma_step(const unsigned short* wt, const unsigned short* gt,
                                          f32x4 (&acc)[MT][4],
                                          int wo, int wn, int quad, int l15, int blkid)
{
#pragma unroll
    for (int st = 0; st < 2; ++st) {
        short8 af[MT], bfv[4];
        const int qb = st * 4 + quad;
#pragma unroll
        for (int i = 0; i < MT; i++) {
            const int orow = wo * WM + i * 16 + l15;
            af[i] = *(const short8*)&wt[orow * 64 + ((qb ^ blkid) << 3)];
        }
#pragma unroll
        for (int t = 0; t < 4; t++) {
            const int nrow = wn * 64 + t * 16 + l15;
            bfv[t] = *(const short8*)&gt[nrow * 64 + ((qb ^ blkid) << 3)];
        }
#pragma unroll
        for (int i = 0; i < MT; i++)
#pragma unroll
            for (int t = 0; t < 4; t++)
                acc[i][t] = __builtin_amdgcn_mfma_f32_16x16x32_bf16(
                    af[i], bfv[t], acc[i][t], 0, 0, 0);
    }
}

// w1 -> bf16 [256][192]; w2 -> fp8 [128][768] k-permuted; w3 -> fp8 [64][384] k-permuted
__global__ void prep_all(const float* __restrict__ w1, unsigned short* __restrict__ wq1,
                         const float* __restrict__ w2, unsigned char* __restrict__ wq2,
                         const float* __restrict__ w3, unsigned char* __restrict__ wq3)
{
    const int tid = blockIdx.x * blockDim.x + threadIdx.x;
    const int stride = gridDim.x * blockDim.x;
    for (int i = tid; i < 256 * 192; i += stride) {
        int o = i / 192, kp = i - o * 192;
        int j = kp >> 6, c = kp & 63;
        wq1[i] = f2bf(w1[(o * 64 + c) * 3 + j]);
    }
    // dest byte r0 within row -> inverse perm -> orig k' (4 consecutive share j)
    for (int i = tid; i < (128 * 768) >> 2; i += stride) {
        const int e0 = i << 2;
        const int o = e0 / 768, r0 = e0 - o * 768;
        const int kc = r0 >> 7, ro = r0 & 127;
        const int k0 = ((ro >> 6) << 6) + (((ro >> 3) & 1) << 5) + (((ro >> 4) & 3) << 3) + (ro & 7);
        const int kp0 = kc * 128 + k0;
        const int j = kp0 >> 8, c0 = kp0 & 255;
        const float* src = &w2[(o * 256 + c0) * 3 + j];
        float f0 = src[0], f1 = src[3], f2 = src[6], f3 = src[9];
        int r = __builtin_amdgcn_cvt_pk_fp8_f32(f0, f1, 0, false);
        r = __builtin_amdgcn_cvt_pk_fp8_f32(f2, f3, r, true);
        *(unsigned int*)&wq2[e0] = (unsigned int)r;
    }
    for (int i = tid; i < (64 * 384) >> 2; i += stride) {
        const int e0 = i << 2;
        const int o = e0 / 384, r0 = e0 - o * 384;
        const int kc = r0 >> 7, ro = r0 & 127;
        const int k0 = ((ro >> 6) << 6) + (((ro >> 3) & 1) << 5) + (((ro >> 4) & 3) << 3) + (ro & 7);
        const int kp0 = kc * 128 + k0;
        const int j = kp0 >> 7, c0 = kp0 & 127;
        const float* src = &w3[(o * 128 + c0) * 3 + j];
        float f0 = src[0], f1 = src[3], f2 = src[6], f3 = src[9];
        int r = __builtin_amdgcn_cvt_pk_fp8_f32(f0, f1, 0, false);
        r = __builtin_amdgcn_cvt_pk_fp8_f32(f2, f3, r, true);
        *(unsigned int*)&wq3[e0] = (unsigned int)r;
    }
}

// data [128][64][1024] f32 -> xT [nB][1024][64] bf16 (tower select on b>=128)
// block (0,0) also re-inits sums/pmax (replaces 2 hipMemsetAsync dispatches)
__global__ __launch_bounds__(256) void transpose_in(const float* __restrict__ inA,
                                                    const float* __restrict__ inB,
                                                    unsigned short* __restrict__ xT,
                                                    float* __restrict__ sums,
                                                    unsigned int* __restrict__ pmax)
{
    const int b = blockIdx.y, n0 = blockIdx.x * 64;
    const float* in = (b >= 128 ? inB : inA) + ((size_t)(b & 127) * 64) * 1024;
    const int tid = threadIdx.x;
    if (blockIdx.x == 0 && blockIdx.y == 0) {
        const int nBv = gridDim.y;
        for (int i = tid; i < 3 * nBv * 2; i += 256) sums[i] = 0.0f;
        for (int i = tid; i < nBv * 64; i += 256) pmax[i] = 0xFFFFFFFFu;
    }
    __shared__ float tile[64][65];
    const int nn = tid & 63, cw = tid >> 6;
#pragma unroll
    for (int i = 0; i < 16; i++) {
        int c = i * 4 + cw;
        tile[c][nn] = in[(size_t)c * 1024 + n0 + nn];
    }
    __syncthreads();
    const int n = tid >> 2, cp = (tid & 3) * 16;
    unsigned int pk[8];
#pragma unroll
    for (int i = 0; i < 8; i++) {
        unsigned short lo = f2bf(tile[cp + 2 * i][n]);
        unsigned short hi = f2bf(tile[cp + 2 * i + 1][n]);
        pk[i] = (unsigned int)lo | ((unsigned int)hi << 16);
    }
    unsigned short* dst = xT + ((size_t)b * 1024 + n0 + n) * 64 + cp;
    uint4 v0 = {pk[0], pk[1], pk[2], pk[3]};
    uint4 v1 = {pk[4], pk[5], pk[6], pk[7]};
    *(uint4*)dst = v0;
    *(uint4*)(dst + 8) = v1;
}

// apply lrelu(norm(.)) ONCE per element (in place). u4PerB = uint4s per batch row.
// operates on k-permuted data; elementwise -> permutation-agnostic.
__global__ __launch_bounds__(256) void norm_act_fp8(unsigned char* __restrict__ a,
                                                    const float* __restrict__ sums,
                                                    float count, int u4PerB)
{
    const int b = blockIdx.y;
    float2 st = stats_from(sums, b, count);
    const float na = st.y, nc = -st.x * st.y;
    uint4* p = (uint4*)a + (size_t)b * u4PerB;
    for (int idx = blockIdx.x * 256 + threadIdx.x; idx < u4PerB; idx += gridDim.x * 256) {
        uint4 v = p[idx];
        v.x = fp8x4_nact(v.x, na, nc);
        v.y = fp8x4_nact(v.y, na, nc);
        v.z = fp8x4_nact(v.z, na, nc);
        v.w = fp8x4_nact(v.w, na, nc);
        p[idx] = v;
    }
}

// R14: convs are ADDRESS-ISSUE bound -> fewer/fatter requests (LDS-packed dense
// epilogue stores, 12B idx loads). R15: a1 channels written k-PERMUTED (perm128)
// so conv2 can read fp8 fragments as b128.
__global__ __launch_bounds__(256, 3) void conv1_mfma(
    const unsigned short* __restrict__ xT,   // [nB][1024][64] bf16
    const int* __restrict__ idxA,            // [128][3069]
    const int* __restrict__ idxB,
    const unsigned short* __restrict__ wq,   // [256][192] bf16 (k'=j*64+c)
    const float* __restrict__ bias,          // [256] f32
    unsigned char* __restrict__ out,         // [nB][1024][256] fp8 raw (k-permuted)
    float* __restrict__ sums)                // [nB][2]
{
    const int b   = blockIdx.x;
    const int o0  = blockIdx.y * 128;
    const int nt0 = blockIdx.z << 7;
    const int tid = threadIdx.x;
    const int lane = tid & 63, wave = tid >> 6;
    const int wo = wave & 1, wn = wave >> 1;
    const int quad = lane >> 4, l15 = lane & 15;
    const int blkid = lane & 7;

    __shared__ __align__(16) unsigned short wt[128 * 64];
    __shared__ __align__(16) unsigned short gt[128 * 64];

    f32x4 acc[4][4];
#pragma unroll
    for (int i = 0; i < 4; i++)
#pragma unroll
        for (int t = 0; t < 4; t++) acc[i][t] = (f32x4){0.f, 0.f, 0.f, 0.f};

    const unsigned short* xTb = xT + (((size_t)b) << 10) * 64;
    const int* idxb = (b >= 128 ? idxB : idxA) + (size_t)(b & 127) * 3069;

    const int gr = tid >> 1, gh = tid & 1;       // gt row (n), 32-channel half
    int s0, s1, s2;
    {
        int n = nt0 + gr;
        int t0 = (n == 0) ? 0 : (n - 1);         // n==0 row is garbage, zeroed later
        const Int3 sv = *(const Int3*)&idxb[3 * t0];
        s0 = sv.x; s1 = sv.y; s2 = sv.z;
    }
    const int wr = tid >> 1, wseg = tid & 1;     // wt row (o), 64B-half
    const unsigned short* wrow = wq + (size_t)(o0 + wr) * 192 + wseg * 32;
    const int gswz = gr & 7, wswz = wr & 7;

    uint4 g0A, g1A, g2A, g3A;
    uint4 g0B, g1B, g2B, g3B;

#define LOADC(S, KC) {                                                           \
        const int src_ = ((KC) == 0) ? s0 : (((KC) == 1) ? s1 : s2);             \
        const uint4* gp_ = (const uint4*)(xTb + (size_t)src_ * 64 + gh * 32);    \
        g0##S = gp_[0]; g1##S = gp_[1]; g2##S = gp_[2]; g3##S = gp_[3];          \
    }

// weights 1-deep here (L2-hot; latency hidden under the gt LDS writes)
#define STAGE(S, KC) {                                                           \
        const uint4* wp_ = (const uint4*)(wrow + ((KC) << 6));                   \
        uint4 wv0 = wp_[0], wv1 = wp_[1], wv2 = wp_[2], wv3 = wp_[3];            \
        *(uint4*)&gt[gr * 64 + (((gh << 2) | 0) ^ gswz) * 8] = g0##S;            \
        *(uint4*)&gt[gr * 64 + (((gh << 2) | 1) ^ gswz) * 8] = g1##S;            \
        *(uint4*)&gt[gr * 64 + (((gh << 2) | 2) ^ gswz) * 8] = g2##S;            \
        *(uint4*)&gt[gr * 64 + (((gh << 2) | 3) ^ gswz) * 8] = g3##S;            \
        *(uint4*)&wt[wr * 64 + ((wseg * 4 + 0) ^ wswz) * 8] = wv0;               \
        *(uint4*)&wt[wr * 64 + ((wseg * 4 + 1) ^ wswz) * 8] = wv1;               \
        *(uint4*)&wt[wr * 64 + ((wseg * 4 + 2) ^ wswz) * 8] = wv2;               \
        *(uint4*)&wt[wr * 64 + ((wseg * 4 + 3) ^ wswz) * 8] = wv3;               \
    }

    // 3 chunks, 2-deep register pipeline, odd tail
    LOADC(A, 0);
    LOADC(B, 1);
    int kc = 0;
    for (; kc + 2 <= 3; kc += 2) {
        if (kc) __syncthreads();
        STAGE(A, kc);
        if (kc + 2 < 3) LOADC(A, kc + 2);
        __syncthreads();
        mfma_step<4, 64>(wt, gt, acc, wo, wn, quad, l15, blkid);
        __syncthreads();
        STAGE(B, kc + 1);
        __syncthreads();
        mfma_step<4, 64>(wt, gt, acc, wo, wn, quad, l15, blkid);
    }
    {   // tail chunk 2 (set A)
        __syncthreads();
        STAGE(A, 2);
        __syncthreads();
        mfma_step<4, 64>(wt, gt, acc, wo, wn, quad, l15, blkid);
    }
#undef LOADC
#undef STAGE

    __syncthreads();                 // all LDS readers done (also fixes red race)
    unsigned char* eb = (unsigned char*)gt;   // [128 n][128 o'] fp8, bank-swizzled
    float lsum = 0.f, lsq = 0.f;
#pragma unroll
    for (int i = 0; i < 4; i++) {
        const int obl = wo * 64 + i * 16 + quad * 4;
        const int op  = perm128(obl);         // R15: channel remap (aligned-4 safe)
        const float4 bv = *(const float4*)(bias + o0 + obl);
#pragma unroll
        for (int t = 0; t < 4; t++) {
            const int nl = wn * 64 + t * 16 + l15;
            float v0 = acc[i][t][0] + bv.x;
            float v1 = acc[i][t][1] + bv.y;
            float v2 = acc[i][t][2] + bv.z;
            float v3 = acc[i][t][3] + bv.w;
            if (nt0 + nl == 0) { v0 = v1 = v2 = v3 = 0.f; }
            lsum += v0 + v1 + v2 + v3;
            lsq  += v0 * v0 + v1 * v1 + v2 * v2 + v3 * v3;
            int r = __builtin_amdgcn_cvt_pk_fp8_f32(v0, v1, 0, false);
            r = __builtin_amdgcn_cvt_pk_fp8_f32(v2, v3, r, true);
            *(unsigned int*)&eb[nl * 128 + (op ^ ((nl & 7) << 4))] = (unsigned int)r;
        }
    }
#pragma unroll
    for (int off = 32; off > 0; off >>= 1) {
        lsum += __shfl_down(lsum, off);
        lsq  += __shfl_down(lsq, off);
    }
    float* red = (float*)wt;
    if (lane == 0) { red[wave] = lsum; red[4 + wave] = lsq; }
    __syncthreads();
    // dense store: 128 rows x 128B tile -> 16B/lane
#pragma unroll
    for (int c = 0; c < 4; ++c) {
        const int ch = c * 256 + tid;
        const int row = ch >> 3, off = (ch & 7) << 4;
        uint4 v = *(const uint4*)&eb[row * 128 + (off ^ ((row & 7) << 4))];
        *(uint4*)&out[((size_t)b * 1024 + nt0 + row) * 256 + o0 + off] = v;
    }
    if (tid == 0) {
        atomicAdd(&sums[2 * b + 0], red[0] + red[1] + red[2] + red[3]);
        atomicAdd(&sums[2 * b + 1], red[4] + red[5] + red[6] + red[7]);
    }
}

// conv2: pure-copy-stage fp8 x fp8 MFMA on k-permuted data. R15: fragment reads
// are b128 pairs (st=2p,2p+1) at col p*4+quad -> bf16-identical 0-conflict
// geometry, half the LDS read instructions. Output a2 fp8, channel-permuted.
__global__ __launch_bounds__(256, 3) void conv2_fp8(
    const unsigned char* __restrict__ a1,    // [nB][1024][256] fp8, normalized, permuted
    const int* __restrict__ idxA,
    const int* __restrict__ idxB,
    const unsigned char* __restrict__ wq8,   // [128][768] fp8 e4m3, k-permuted
    const float* __restrict__ bias,          // [128] f32
    unsigned char* __restrict__ out,         // [nB][1024][128] fp8 raw (permuted)
    float* __restrict__ sums)                // [nB][2]
{
    const int b   = blockIdx.x;
    const int nt0 = blockIdx.z << 7;
    const int tid = threadIdx.x;
    const int lane = tid & 63, wave = tid >> 6;
    const int wo = wave & 1, wn = wave >> 1;
    const int quad = lane >> 4, l15 = lane & 15;
    const int blkid = lane & 7;

    __shared__ __align__(16) unsigned char wt8[128 * 128];
    __shared__ __align__(16) unsigned char gt8[128 * 128];

    f32x4 acc[4][4];
#pragma unroll
    for (int i = 0; i < 4; i++)
#pragma unroll
        for (int t = 0; t < 4; t++) acc[i][t] = (f32x4){0.f, 0.f, 0.f, 0.f};

    const unsigned char* xb = a1 + (((size_t)b) << 10) * 256;
    const int* idxb = (b >= 128 ? idxB : idxA) + (size_t)(b & 127) * 3069;

    const int gr = tid >> 1, gh = tid & 1;   // row, 64B-half (same for gt and wt)
    int si0, si1, si2;
    {
        int n = nt0 + gr;
        int t0 = (n == 0) ? 0 : (n - 1);
        const Int3 sv = *(const Int3*)&idxb[3 * t0];
        si0 = sv.x; si1 = sv.y; si2 = sv.z;
    }
    const unsigned char* wrow = wq8 + (size_t)gr * 768 + gh * 64;
    const int swz = gr & 7;

    uint4 g0A, g1A, g2A, g3A;
    uint4 g0B, g1B, g2B, g3B;

#define LOADC2(S, KC) {                                                          \
        const int j_  = (KC) >> 1;                                               \
        const int c0_ = ((KC) & 1) << 7;                                         \
        const int src_ = (j_ == 0) ? si0 : ((j_ == 1) ? si1 : si2);              \
        const uint4* gp_ = (const uint4*)(xb + (size_t)src_ * 256 + c0_ + gh * 64); \
        g0##S = gp_[0]; g1##S = gp_[1]; g2##S = gp_[2]; g3##S = gp_[3];          \
    }

#define STAGE2(S, KC) {                                                          \
        const uint4* wp_ = (const uint4*)(wrow + (KC) * 128);                    \
        uint4 wv0 = wp_[0], wv1 = wp_[1], wv2 = wp_[2], wv3 = wp_[3];            \
        *(uint4*)&gt8[gr * 128 + (((gh << 2) | 0) ^ swz) * 16] = g0##S;          \
        *(uint4*)&gt8[gr * 128 + (((gh << 2) | 1) ^ swz) * 16] = g1##S;          \
        *(uint4*)&gt8[gr * 128 + (((gh << 2) | 2) ^ swz) * 16] = g2##S;          \
        *(uint4*)&gt8[gr * 128 + (((gh << 2) | 3) ^ swz) * 16] = g3##S;          \
        *(uint4*)&wt8[gr * 128 + (((gh << 2) | 0) ^ swz) * 16] = wv0;            \
        *(uint4*)&wt8[gr * 128 + (((gh << 2) | 1) ^ swz) * 16] = wv1;            \
        *(uint4*)&wt8[gr * 128 + (((gh << 2) | 2) ^ swz) * 16] = wv2;            \
        *(uint4*)&wt8[gr * 128 + (((gh << 2) | 3) ^ swz) * 16] = wv3;            \
    }

#define MFMA_STEP2 {                                                             \
        _Pragma("unroll")                                                        \
        for (int pp = 0; pp < 2; ++pp) {                                         \
            ulonglong2 a0v, a1v, a2v, a3v, b0v, b1v, b2v, b3v;                   \
            {                                                                    \
                const int cx = (((pp * 4 + quad) ^ blkid) << 4);                 \
                a0v = *(const ulonglong2*)&wt8[(wo * 64 +  0 + l15) * 128 + cx]; \
                a1v = *(const ulonglong2*)&wt8[(wo * 64 + 16 + l15) * 128 + cx]; \
                a2v = *(const ulonglong2*)&wt8[(wo * 64 + 32 + l15) * 128 + cx]; \
                a3v = *(const ulonglong2*)&wt8[(wo * 64 + 48 + l15) * 128 + cx]; \
                b0v = *(const ulonglong2*)&gt8[(wn * 64 +  0 + l15) * 128 + cx]; \
                b1v = *(const ulonglong2*)&gt8[(wn * 64 + 16 + l15) * 128 + cx]; \
                b2v = *(const ulonglong2*)&gt8[(wn * 64 + 32 + l15) * 128 + cx]; \
                b3v = *(const ulonglong2*)&gt8[(wn * 64 + 48 + l15) * 128 + cx]; \
            }                                                                    \
            acc[0][0] = __builtin_amdgcn_mfma_f32_16x16x32_fp8_fp8((long)a0v.x, (long)b0v.x, acc[0][0], 0, 0, 0); \
            acc[0][1] = __builtin_amdgcn_mfma_f32_16x16x32_fp8_fp8((long)a0v.x, (long)b1v.x, acc[0][1], 0, 0, 0); \
            acc[0][2] = __builtin_amdgcn_mfma_f32_16x16x32_fp8_fp8((long)a0v.x, (long)b2v.x, acc[0][2], 0, 0, 0); \
            acc[0][3] = __builtin_amdgcn_mfma_f32_16x16x32_fp8_fp8((long)a0v.x, (long)b3v.x, acc[0][3], 0, 0, 0); \
            acc[1][0] = __builtin_amdgcn_mfma_f32_16x16x32_fp8_fp8((long)a1v.x, (long)b0v.x, acc[1][0], 0, 0, 0); \
            acc[1][1] = __builtin_amdgcn_mfma_f32_16x16x32_fp8_fp8((long)a1v.x, (long)b1v.x, acc[1][1], 0, 0, 0); \
            acc[1][2] = __builtin_amdgcn_mfma_f32_16x16x32_fp8_fp8((long)a1v.x, (long)b2v.x, acc[1][2], 0, 0, 0); \
            acc[1][3] = __builtin_amdgcn_mfma_f32_16x16x32_fp8_fp8((long)a1v.x, (long)b3v.x, acc[1][3], 0, 0, 0); \
            acc[2][0] = __builtin_amdgcn_mfma_f32_16x16x32_fp8_fp8((long)a2v.x, (long)b0v.x, acc[2][0], 0, 0, 0); \
            acc[2][1] = __builtin_amdgcn_mfma_f32_16x16x32_fp8_fp8((long)a2v.x, (long)b1v.x, acc[2][1], 0, 0, 0); \
            acc[2][2] = __builtin_amdgcn_mfma_f32_16x16x32_fp8_fp8((long)a2v.x, (long)b2v.x, acc[2][2], 0, 0, 0); \
            acc[2][3] = __builtin_amdgcn_mfma_f32_16x16x32_fp8_fp8((long)a2v.x, (long)b3v.x, acc[2][3], 0, 0, 0); \
            acc[3][0] = __builtin_amdgcn_mfma_f32_16x16x32_fp8_fp8((long)a3v.x, (long)b0v.x, acc[3][0], 0, 0, 0); \
            acc[3][1] = __builtin_amdgcn_mfma_f32_16x16x32_fp8_fp8((long)a3v.x, (long)b1v.x, acc[3][1], 0, 0, 0); \
            acc[3][2] = __builtin_amdgcn_mfma_f32_16x16x32_fp8_fp8((long)a3v.x, (long)b2v.x, acc[3][2], 0, 0, 0); \
            acc[3][3] = __builtin_amdgcn_mfma_f32_16x16x32_fp8_fp8((long)a3v.x, (long)b3v.x, acc[3][3], 0, 0, 0); \
            acc[0][0] = __builtin_amdgcn_mfma_f32_16x16x32_fp8_fp8((long)a0v.y, (long)b0v.y, acc[0][0], 0, 0, 0); \
            acc[0][1] = __builtin_amdgcn_mfma_f32_16x16x32_fp8_fp8((long)a0v.y, (long)b1v.y, acc[0][1], 0, 0, 0); \
            acc[0][2] = __builtin_amdgcn_mfma_f32_16x16x32_fp8_fp8((long)a0v.y, (long)b2v.y, acc[0][2], 0, 0, 0); \
            acc[0][3] = __builtin_amdgcn_mfma_f32_16x16x32_fp8_fp8((long)a0v.y, (long)b3v.y, acc[0][3], 0, 0, 0); \
            acc[1][0] = __builtin_amdgcn_mfma_f32_16x16x32_fp8_fp8((long)a1v.y, (long)b0v.y, acc[1][0], 0, 0, 0); \
            acc[1][1] = __builtin_amdgcn_mfma_f32_16x16x32_fp8_fp8((long)a1v.y, (long)b1v.y, acc[1][1], 0, 0, 0); \
            acc[1][2] = __builtin_amdgcn_mfma_f32_16x16x32_fp8_fp8((long)a1v.y, (long)b2v.y, acc[1][2], 0, 0, 0); \
            acc[1][3] = __builtin_amdgcn_mfma_f32_16x16x32_fp8_fp8((long)a1v.y, (long)b3v.y, acc[1][3], 0, 0, 0); \
            acc[2][0] = __builtin_amdgcn_mfma_f32_16x16x32_fp8_fp8((long)a2v.y, (long)b0v.y, acc[2][0], 0, 0, 0); \
            acc[2][1] = __builtin_amdgcn_mfma_f32_16x16x32_fp8_fp8((long)a2v.y, (long)b1v.y, acc[2][1], 0, 0, 0); \
            acc[2][2] = __builtin_amdgcn_mfma_f32_16x16x32_fp8_fp8((long)a2v.y, (long)b2v.y, acc[2][2], 0, 0, 0); \
            acc[2][3] = __builtin_amdgcn_mfma_f32_16x16x32_fp8_fp8((long)a2v.y, (long)b3v.y, acc[2][3], 0, 0, 0); \
            acc[3][0] = __builtin_amdgcn_mfma_f32_16x16x32_fp8_fp8((long)a3v.y, (long)b0v.y, acc[3][0], 0, 0, 0); \
            acc[3][1] = __builtin_amdgcn_mfma_f32_16x16x32_fp8_fp8((long)a3v.y, (long)b1v.y, acc[3][1], 0, 0, 0); \
            acc[3][2] = __builtin_amdgcn_mfma_f32_16x16x32_fp8_fp8((long)a3v.y, (long)b2v.y, acc[3][2], 0, 0, 0); \
            acc[3][3] = __builtin_amdgcn_mfma_f32_16x16x32_fp8_fp8((long)a3v.y, (long)b3v.y, acc[3][3], 0, 0, 0); \
        }                                                                        \
    }

    LOADC2(A, 0);
    LOADC2(B, 1);
    int kc = 0;
    for (; kc + 2 <= 6; kc += 2) {
        if (kc) __syncthreads();
        STAGE2(A, kc);
        if (kc + 2 < 6) LOADC2(A, kc + 2);
        __syncthreads();
        MFMA_STEP2;
        __syncthreads();
        STAGE2(B, kc + 1);
        if (kc + 3 < 6) LOADC2(B, kc + 3);
        __syncthreads();
        MFMA_STEP2;
    }
#undef LOADC2
#undef STAGE2
#undef MFMA_STEP2

    __syncthreads();                 // all LDS readers done
    unsigned char* eb = gt8;         // [128 n][128 o'] fp8, bank-swizzled
    float lsum = 0.f, lsq = 0.f;
#pragma unroll
    for (int i = 0; i < 4; i++) {
        const int obl = wo * 64 + i * 16 + quad * 4;
        const int op  = perm128(obl);         // R15: channel remap for a2
        const float4 bv = *(const float4*)(bias + obl);
#pragma unroll
        for (int t = 0; t < 4; t++) {
            const int nl = wn * 64 + t * 16 + l15;
            float v0 = acc[i][t][0] + bv.x;
            float v1 = acc[i][t][1] + bv.y;
            float v2 = acc[i][t][2] + bv.z;
            float v3 = acc[i][t][3] + bv.w;
            if (nt0 + nl == 0) { v0 = v1 = v2 = v3 = 0.f; }
            lsum += v0 + v1 + v2 + v3;
            lsq  += v0 * v0 + v1 * v1 + v2 * v2 + v3 * v3;
            int r = __builtin_amdgcn_cvt_pk_fp8_f32(v0, v1, 0, false);
            r = __builtin_amdgcn_cvt_pk_fp8_f32(v2, v3, r, true);
            *(unsigned int*)&eb[nl * 128 + (op ^ ((nl & 7) << 4))] = (unsigned int)r;
        }
    }
#pragma unroll
    for (int off = 32; off > 0; off >>= 1) {
        lsum += __shfl_down(lsum, off);
        lsq  += __shfl_down(lsq, off);
    }
    float* red = (float*)wt8;
    if (lane == 0) { red[wave] = lsum; red[4 + wave] = lsq; }
    __syncthreads();
#pragma unroll
    for (int c = 0; c < 4; ++c) {
        const int ch = c * 256 + tid;
        const int row = ch >> 3, off = (ch & 7) << 4;
        uint4 v = *(const uint4*)&eb[row * 128 + (off ^ ((row & 7) << 4))];
        *(uint4*)&out[((size_t)b * 1024 + nt0 + row) * 128 + off] = v;
    }
    if (tid == 0) {
        atomicAdd(&sums[2 * b + 0], red[0] + red[1] + red[2] + red[3]);
        atomicAdd(&sums[2 * b + 1], red[4] + red[5] + red[6] + red[7]);
    }
}

// conv3: pure-copy fp8 x fp8 MFMA on k-permuted a2. b128 paired fragment reads.
// O=64, Cin=128, K=384 -> 3 chunks. POOL epilogue (no stores, LINEAR channels).
__global__ __launch_bounds__(256, 3) void conv3_fp8(
    const unsigned char* __restrict__ a2,    // [nB][1024][128] fp8, normalized, permuted
    const int* __restrict__ idxA,
    const int* __restrict__ idxB,
    const unsigned char* __restrict__ wq8,   // [64][384] fp8 e4m3, k-permuted
    const float* __restrict__ bias,          // [64] f32
    float* __restrict__ sums,                // [nB][2]
    float* __restrict__ pmax)                // [nB][64]
{
    const int b   = blockIdx.x;
    const int nt0 = blockIdx.z << 7;
    const int tid = threadIdx.x;
    const int lane = tid & 63, wave = tid >> 6;
    const int wo = wave & 1, wn = wave >> 1;
    const int quad = lane >> 4, l15 = lane & 15;
    const int blkid = lane & 7;

    __shared__ __align__(16) unsigned char wt8[64 * 128];
    __shared__ __align__(16) unsigned char gt8[128 * 128];

    f32x4 acc[2][4];
#pragma unroll
    for (int i = 0; i < 2; i++)
#pragma unroll
        for (int t = 0; t < 4; t++) acc[i][t] = (f32x4){0.f, 0.f, 0.f, 0.f};

    const unsigned char* xb = a2 + (((size_t)b) << 10) * 128;
    const int* idxb = (b >= 128 ? idxB : idxA) + (size_t)(b & 127) * 3069;

    const int gr = tid >> 1, gh = tid & 1;       // gt row, 64B-half
    int si0, si1, si2;
    {
        int n = nt0 + gr;
        int t0 = (n == 0) ? 0 : (n - 1);
        const Int3 sv = *(const Int3*)&idxb[3 * t0];
        si0 = sv.x; si1 = sv.y; si2 = sv.z;
    }
    const int wr = tid >> 2, wseg = tid & 3;     // wt row (o), 32B segment
    const unsigned char* wrow = wq8 + (size_t)wr * 384 + wseg * 32;
    const int gswz = gr & 7, wswz = wr & 7;

    uint4 g0A, g1A, g2A, g3A;
    uint4 g0B, g1B, g2B, g3B;

#define LOADC3(S, KC) {                                                          \
        const int src_ = ((KC) == 0) ? si0 : (((KC) == 1) ? si1 : si2);          \
        const uint4* gp_ = (const uint4*)(xb + (size_t)src_ * 128 + gh * 64);    \
        g0##S = gp_[0]; g1##S = gp_[1]; g2##S = gp_[2]; g3##S = gp_[3];          \
    }

#define STAGE3(S, KC) {                                                          \
        const uint4* wp_ = (const uint4*)(wrow + (KC) * 128);                    \
        uint4 wv0 = wp_[0], wv1 = wp_[1];                                        \
        *(uint4*)&gt8[gr * 128 + (((gh << 2) | 0) ^ gswz) * 16] = g0##S;         \
        *(uint4*)&gt8[gr * 128 + (((gh << 2) | 1) ^ gswz) * 16] = g1##S;         \
        *(uint4*)&gt8[gr * 128 + (((gh << 2) | 2) ^ gswz) * 16] = g2##S;         \
        *(uint4*)&gt8[gr * 128 + (((gh << 2) | 3) ^ gswz) * 16] = g3##S;         \
        *(uint4*)&wt8[wr * 128 + (((wseg << 1) | 0) ^ wswz) * 16] = wv0;         \
        *(uint4*)&wt8[wr * 128 + (((wseg << 1) | 1) ^ wswz) * 16] = wv1;         \
    }

#define MFMA_STEP3 {                                                             \
        _Pragma("unroll")                                                        \
        for (int pp = 0; pp < 2; ++pp) {                                         \
            ulonglong2 a0v, a1v, b0v, b1v, b2v, b3v;                             \
            {                                                                    \
                const int cx = (((pp * 4 + quad) ^ blkid) << 4);                 \
                a0v = *(const ulonglong2*)&wt8[(wo * 32 +  0 + l15) * 128 + cx]; \
                a1v = *(const ulonglong2*)&wt8[(wo * 32 + 16 + l15) * 128 + cx]; \
                b0v = *(const ulonglong2*)&gt8[(wn * 64 +  0 + l15) * 128 + cx]; \
                b1v = *(const ulonglong2*)&gt8[(wn * 64 + 16 + l15) * 128 + cx]; \
                b2v = *(const ulonglong2*)&gt8[(wn * 64 + 32 + l15) * 128 + cx]; \
                b3v = *(const ulonglong2*)&gt8[(wn * 64 + 48 + l15) * 128 + cx]; \
            }                                                                    \
            acc[0][0] = __builtin_amdgcn_mfma_f32_16x16x32_fp8_fp8((long)a0v.x, (long)b0v.x, acc[0][0], 0, 0, 0); \
            acc[0][1] = __builtin_amdgcn_mfma_f32_16x16x32_fp8_fp8((long)a0v.x, (long)b1v.x, acc[0][1], 0, 0, 0); \
            acc[0][2] = __builtin_amdgcn_mfma_f32_16x16x32_fp8_fp8((long)a0v.x, (long)b2v.x, acc[0][2], 0, 0, 0); \
            acc[0][3] = __builtin_amdgcn_mfma_f32_16x16x32_fp8_fp8((long)a0v.x, (long)b3v.x, acc[0][3], 0, 0, 0); \
            acc[1][0] = __builtin_amdgcn_mfma_f32_16x16x32_fp8_fp8((long)a1v.x, (long)b0v.x, acc[1][0], 0, 0, 0); \
            acc[1][1] = __builtin_amdgcn_mfma_f32_16x16x32_fp8_fp8((long)a1v.x, (long)b1v.x, acc[1][1], 0, 0, 0); \
            acc[1][2] = __builtin_amdgcn_mfma_f32_16x16x32_fp8_fp8((long)a1v.x, (long)b2v.x, acc[1][2], 0, 0, 0); \
            acc[1][3] = __builtin_amdgcn_mfma_f32_16x16x32_fp8_fp8((long)a1v.x, (long)b3v.x, acc[1][3], 0, 0, 0); \
            acc[0][0] = __builtin_amdgcn_mfma_f32_16x16x32_fp8_fp8((long)a0v.y, (long)b0v.y, acc[0][0], 0, 0, 0); \
            acc[0][1] = __builtin_amdgcn_mfma_f32_16x16x32_fp8_fp8((long)a0v.y, (long)b1v.y, acc[0][1], 0, 0, 0); \
            acc[0][2] = __builtin_amdgcn_mfma_f32_16x16x32_fp8_fp8((long)a0v.y, (long)b2v.y, acc[0][2], 0, 0, 0); \
            acc[0][3] = __builtin_amdgcn_mfma_f32_16x16x32_fp8_fp8((long)a0v.y, (long)b3v.y, acc[0][3], 0, 0, 0); \
            acc[1][0] = __builtin_amdgcn_mfma_f32_16x16x32_fp8_fp8((long)a1v.y, (long)b0v.y, acc[1][0], 0, 0, 0); \
            acc[1][1] = __builtin_amdgcn_mfma_f32_16x16x32_fp8_fp8((long)a1v.y, (long)b1v.y, acc[1][1], 0, 0, 0); \
            acc[1][2] = __builtin_amdgcn_mfma_f32_16x16x32_fp8_fp8((long)a1v.y, (long)b2v.y, acc[1][2], 0, 0, 0); \
            acc[1][3] = __builtin_amdgcn_mfma_f32_16x16x32_fp8_fp8((long)a1v.y, (long)b3v.y, acc[1][3], 0, 0, 0); \
        }                                                                        \
    }

    LOADC3(A, 0);
    LOADC3(B, 1);
    int kc = 0;
    for (; kc + 2 <= 3; kc += 2) {
        if (kc) __syncthreads();
        STAGE3(A, kc);
        if (kc + 2 < 3) LOADC3(A, kc + 2);
        __syncthreads();
        MFMA_STEP3;
        __syncthreads();
        STAGE3(B, kc + 1);
        __syncthreads();
        MFMA_STEP3;
    }
    {   // tail chunk 2 (set A)
        __syncthreads();
        STAGE3(A, 2);
        __syncthreads();
        MFMA_STEP3;
    }
#undef LOADC3
#undef STAGE3
#undef MFMA_STEP3

    __syncthreads();                 // all LDS readers done before red overlay
    float lsum = 0.f, lsq = 0.f;
#pragma unroll
    for (int i = 0; i < 2; i++) {
        const int ob = wo * 32 + i * 16 + quad * 4;
        const float4 bv = *(const float4*)(bias + ob);
        float mx0 = -1e30f, mx1 = -1e30f, mx2 = -1e30f, mx3 = -1e30f;
#pragma unroll
        for (int t = 0; t < 4; t++) {
            const int n = nt0 + wn * 64 + t * 16 + l15;
            float v0 = acc[i][t][0] + bv.x;
            float v1 = acc[i][t][1] + bv.y;
            float v2 = acc[i][t][2] + bv.z;
            float v3 = acc[i][t][3] + bv.w;
            if (n == 0) { v0 = v1 = v2 = v3 = 0.f; }
            lsum += v0 + v1 + v2 + v3;
            lsq  += v0 * v0 + v1 * v1 + v2 * v2 + v3 * v3;
            mx0 = fmaxf(mx0, v0); mx1 = fmaxf(mx1, v1);
            mx2 = fmaxf(mx2, v2); mx3 = fmaxf(mx3, v3);
        }
#pragma unroll
        for (int off = 1; off < 16; off <<= 1) {
            mx0 = fmaxf(mx0, __shfl_xor(mx0, off));
            mx1 = fmaxf(mx1, __shfl_xor(mx1, off));
            mx2 = fmaxf(mx2, __shfl_xor(mx2, off));
            mx3 = fmaxf(mx3, __shfl_xor(mx3, off));
        }
        if (l15 == 0) {
            atomicMaxF(&pmax[(size_t)b * 64 + ob + 0], mx0);
            atomicMaxF(&pmax[(size_t)b * 64 + ob + 1], mx1);
            atomicMaxF(&pmax[(size_t)b * 64 + ob + 2], mx2);
            atomicMaxF(&pmax[(size_t)b * 64 + ob + 3], mx3);
        }
    }
#pragma unroll
    for (int off = 32; off > 0; off >>= 1) {
        lsum += __shfl_down(lsum, off);
        lsq  += __shfl_down(lsq, off);
    }
    float* red = (float*)wt8;
    if (lane == 0) { red[wave] = lsum; red[4 + wave] = lsq; }
    __syncthreads();
    if (tid == 0) {
        atomicAdd(&sums[2 * b + 0], red[0] + red[1] + red[2] + red[3]);
        atomicAdd(&sums[2 * b + 1], red[4] + red[5] + red[6] + red[7]);
    }
}

// pooled max -> normalize -> fc1+lrelu -> fc2
__global__ __launch_bounds__(64) void fc_head(
    const float* __restrict__ pmax, const float* __restrict__ sums3, float count,
    const float* __restrict__ w_fc1, const float* __restrict__ b_fc1,
    const float* __restrict__ w_fc2, const float* __restrict__ b_fc2,
    float* __restrict__ y)
{
    const int b = blockIdx.x, t = threadIdx.x;
    __shared__ float pooled[64];
    __shared__ float hid[32];
    float2 s = stats_from(sums3, b, count);
    pooled[t] = (pmax[(size_t)b * 64 + t] - s.x) * s.y;
    __syncthreads();
    if (t < 32) {
        float h = b_fc1[t];
#pragma unroll
        for (int c = 0; c < 64; c++) h += pooled[c] * w_fc1[t * 64 + c];
        hid[t] = LRELU(h);
    }
    __syncthreads();
    if (t == 0) {
        float v = b_fc2[0];
#pragma unroll
        for (int c = 0; c < 32; c++) v += hid[c] * w_fc2[c];
        y[b] = v;
    }
}

__global__ void sigmoid_diff(const float* __restrict__ y1,
                             const float* __restrict__ y2,
                             float* __restrict__ out)
{
    int b = threadIdx.x;
    if (b < 128) out[b] = 1.0f / (1.0f + expf(-(y1[b] - y2[b])));
}

extern "C" void kernel_launch(void* const* d_in, const int* in_sizes, int n_in,
                              void* d_out, int out_size, void* d_ws, size_t ws_size,
                              hipStream_t stream)
{
    const float* data1 = (const float*)d_in[0];
    const int*   idx1  = (const int*)d_in[1];
    const float* data2 = (const float*)d_in[2];
    const int*   idx2  = (const int*)d_in[3];
    const float* w1 = (const float*)d_in[4];
    const float* b1 = (const float*)d_in[5];
    const float* w2 = (const float*)d_in[6];
    const float* b2 = (const float*)d_in[7];
    const float* w3 = (const float*)d_in[8];
    const float* b3 = (const float*)d_in[9];
    const float* wfc1 = (const float*)d_in[10];
    const float* bfc1 = (const float*)d_in[11];
    const float* wfc2 = (const float*)d_in[12];
    const float* bfc2 = (const float*)d_in[13];

    // a1 and a2 are fp8 (1B/elem); xT stays bf16
    const size_t needM = (size_t)256 * 1024 * (64 * 2 + 256 * 1 + 128 * 1) + 768 * 1024;
    const bool merged = ws_size >= needM;
    const int nB = merged ? 256 : 128;
    const size_t szXT = (size_t)nB * 1024 * 64 * 2;
    const size_t szA1 = (size_t)nB * 1024 * 256;       // fp8
    const size_t szA2 = (size_t)nB * 1024 * 128;       // fp8

    char* ws = (char*)d_ws;
    unsigned short* xT = (unsigned short*)ws;
    unsigned char*  a1 = (unsigned char*)(ws + szXT);
    unsigned char*  a2 = (unsigned char*)(ws + szXT + szA1);
    char* tail = ws + szXT + szA1 + szA2;
    unsigned short* wq1   = (unsigned short*)tail;               // 96 KB
    unsigned char*  wq2f8 = (unsigned char*)(tail + 128 * 1024); // 96 KB (fp8)
    unsigned char*  wq3f8 = (unsigned char*)(tail + 384 * 1024); // 24 KB (fp8)
    float* sums = (float*)(tail + 448 * 1024);                   // 3*nB*2 f32
    float* pmax = (float*)(tail + 512 * 1024);                   // nB*64 f32
    float* yv   = (float*)(tail + 640 * 1024);                   // 256 f32

    prep_all<<<96, 256, 0, stream>>>(w1, wq1, w2, wq2f8, w3, wq3f8);

    const int nIter = merged ? 1 : 2;
    for (int t = 0; t < nIter; ++t) {
        const float* dA = (merged || t == 0) ? data1 : data2;
        const float* dB = merged ? data2 : dA;
        const int* iA = (merged || t == 0) ? idx1 : idx2;
        const int* iB = merged ? idx2 : iA;
        float* s1 = sums;
        float* s2 = sums + nB * 2;
        float* s3 = sums + nB * 4;

        // sums/pmax re-init folded into transpose_in block (0,0)
        transpose_in<<<dim3(16, nB), 256, 0, stream>>>(dA, dB, xT, sums,
                                                       (unsigned int*)pmax);

        conv1_mfma<<<dim3(nB, 2, 8), 256, 0, stream>>>(
            xT, iA, iB, wq1, b1, a1, s1);

        norm_act_fp8<<<dim3(16, nB), 256, 0, stream>>>(a1, s1, 256.0f * 1024.0f, 16384);

        conv2_fp8<<<dim3(nB, 1, 8), 256, 0, stream>>>(
            a1, iA, iB, wq2f8, b2, a2, s2);

        norm_act_fp8<<<dim3(8, nB), 256, 0, stream>>>(a2, s2, 128.0f * 1024.0f, 8192);

        conv3_fp8<<<dim3(nB, 1, 8), 256, 0, stream>>>(
            a2, iA, iB, wq3f8, b3, s3, pmax);

        fc_head<<<nB, 64, 0, stream>>>(pmax, s3, 64.0f * 1024.0f,
                                       wfc1, bfc1, wfc2, bfc2,
                                       yv + (merged ? 0 : t * 128));
    }
    sigmoid_diff<<<1, 128, 0, stream>>>(yv, yv + 128, (float*)d_out);
}